// Round 4
// 279.773 us; speedup vs baseline: 4.2889x; 4.2889x over previous
//
#include <hip/hip_runtime.h>
#include <hip/hip_bf16.h>

#define L_SEQ 2048
#define HIDN  1024
#define NH    16
#define DHD   64
#define QKV_N 3072

typedef float f4 __attribute__((ext_vector_type(4)));
typedef __bf16 bf16x8 __attribute__((ext_vector_type(8)));
typedef _Float16 half8 __attribute__((ext_vector_type(8)));
typedef unsigned int u32x2 __attribute__((ext_vector_type(2)));

union H8 {
  half8 h;
  u32x2 u2[2];
  uint4 u4;
};

__device__ __forceinline__ float b2f(unsigned short u) {
  union { unsigned int i; float f; } c; c.i = ((unsigned int)u) << 16; return c.f;
}
__device__ __forceinline__ unsigned short f2b(float f) {
  union { float f; unsigned int i; } c; c.f = f;
  unsigned int r = c.i + 0x7FFFu + ((c.i >> 16) & 1u);
  return (unsigned short)(r >> 16);
}
__device__ __forceinline__ unsigned short f2h(float f) {
  union { _Float16 h; unsigned short u; } c; c.h = (_Float16)f; return c.u;
}
__device__ __forceinline__ void unpack8(uint4 u, float* f) {
  unsigned int w[4] = {u.x, u.y, u.z, u.w};
#pragma unroll
  for (int i = 0; i < 4; ++i) {
    union { unsigned int i_; float f_; } lo, hi;
    lo.i_ = w[i] << 16;
    hi.i_ = w[i] & 0xffff0000u;
    f[2 * i] = lo.f_; f[2 * i + 1] = hi.f_;
  }
}

// ---------------- runtime input-dtype detection ----------------
__global__ void detect_kernel(const unsigned short* __restrict__ hs, int* flag) {
  __shared__ int cnt;
  if (threadIdx.x == 0) cnt = 0;
  __syncthreads();
  int c = 0;
  for (int i = threadIdx.x; i < 8192; i += 256) {
    unsigned int e = (hs[i] >> 7) & 0xFFu;
    if (e >= 140u) c++;
  }
  atomicAdd(&cnt, c);
  __syncthreads();
  if (threadIdx.x == 0) *flag = (cnt >= 32) ? 1 : 0;  // 1 = fp32 inputs
}

// ---------------- canonicalize big arrays to bf16 ----------------
__global__ __launch_bounds__(256) void convert_big(const void* __restrict__ in,
                                                   unsigned short* __restrict__ out,
                                                   int n, const int* __restrict__ flag) {
  const int i = (blockIdx.x * 256 + threadIdx.x) * 4;
  if (i >= n) return;
  if (*flag) {
    f4 v = *(const f4*)((const float*)in + i);
    ushort4 o;
    o.x = f2b(v[0]); o.y = f2b(v[1]); o.z = f2b(v[2]); o.w = f2b(v[3]);
    *(ushort4*)(out + i) = o;
  } else {
    *(uint2*)(out + i) = *(const uint2*)((const unsigned short*)in + i);
  }
}

// ---------------- canonicalize small arrays to fp32 ----------------
// layout in smallf: qw@0(2048) qb@2048(1024) kw@3072(2048) kb@5120(1024)
// vw@6144(2048) vb@8192(1024) nw@9216(64) al@9280(16) dt_bias@9296(16)
// dt_proj_b@9312(16) oc@9328(16)  total 9344
__global__ __launch_bounds__(256) void convert_small(
    const void* qw, const void* qb, const void* kw, const void* kb,
    const void* vw, const void* vb, const void* nw, const void* al,
    const void* dtb, const void* dpb, const void* oc,
    float* __restrict__ out, const int* __restrict__ flag) {
  const int f = *flag;
  const void* ptrs[11] = {qw, qb, kw, kb, vw, vb, nw, al, dtb, dpb, oc};
  const int sizes[11] = {2048, 1024, 2048, 1024, 2048, 1024, 64, 16, 16, 16, 16};
  int off = 0;
  for (int a = 0; a < 11; ++a) {
    for (int i = threadIdx.x + blockIdx.x * 256; i < sizes[a]; i += gridDim.x * 256)
      out[off + i] = f ? ((const float*)ptrs[a])[i] : b2f(((const unsigned short*)ptrs[a])[i]);
    off += sizes[a];
  }
}

// ---------------- C = A (MxK) * B^T (NxK), bf16 in, fp32 acc ----------------
template <int MODE>
__global__ __launch_bounds__(256) void gemm_bt(
    const unsigned short* __restrict__ A, const unsigned short* __restrict__ B,
    void* __restrict__ Cv, int M, int N, int K, const int* __restrict__ flag)
{
  __shared__ __align__(16) short As[64 * 40];
  __shared__ __align__(16) short Bs[64 * 40];
  const int t = threadIdx.x;
  const int wave = t >> 6, lane = t & 63;
  const int quad = lane >> 4, l16 = lane & 15;
  const int m0 = blockIdx.y * 64, n0 = blockIdx.x * 64;
  const int srow = t >> 2, scol = (t & 3) * 8;
  f4 acc[4];
#pragma unroll
  for (int i = 0; i < 4; ++i) acc[i] = (f4){0.f, 0.f, 0.f, 0.f};
  const unsigned short* ap = A + (size_t)(m0 + srow) * K + scol;
  const unsigned short* bp = B + (size_t)(n0 + srow) * K + scol;
  for (int k0 = 0; k0 < K; k0 += 32) {
    uint4 av = *(const uint4*)(ap + k0);
    uint4 bv = *(const uint4*)(bp + k0);
    __syncthreads();
    *(uint4*)&As[srow * 40 + scol] = av;
    *(uint4*)&Bs[srow * 40 + scol] = bv;
    __syncthreads();
    bf16x8 af = *(const bf16x8*)&As[(wave * 16 + l16) * 40 + quad * 8];
#pragma unroll
    for (int nt = 0; nt < 4; ++nt) {
      bf16x8 bf = *(const bf16x8*)&Bs[(nt * 16 + l16) * 40 + quad * 8];
      acc[nt] = __builtin_amdgcn_mfma_f32_16x16x32_bf16(af, bf, acc[nt], 0, 0, 0);
    }
  }
  const int outf32 = (MODE == 0) ? 1 : (*flag ? 1 : 0);
#pragma unroll
  for (int nt = 0; nt < 4; ++nt) {
#pragma unroll
    for (int r = 0; r < 4; ++r) {
      int m = m0 + wave * 16 + quad * 4 + r;
      int n = n0 + nt * 16 + l16;
      if (outf32) ((float*)Cv)[(size_t)m * N + n] = acc[nt][r];
      else        ((unsigned short*)Cv)[(size_t)m * N + n] = f2b(acc[nt][r]);
    }
  }
}

// ---------------- dt = softplus(hs @ dtw^T + dt_proj_b + dt_bias) ----------
__global__ __launch_bounds__(256) void dt_kernel(
    const unsigned short* __restrict__ hs,
    const unsigned short* __restrict__ dtw,
    const float* __restrict__ smallf,
    float* __restrict__ dt_out, float* __restrict__ A_out)
{
  const int l = blockIdx.x;
  const int t = threadIdx.x, wave = t >> 6, lane = t & 63;
  const unsigned short* hp = hs + (size_t)l * HIDN + lane * 16;
  float hv[16];
  unpack8(*(const uint4*)hp, hv);
  unpack8(*(const uint4*)(hp + 8), hv + 8);
#pragma unroll
  for (int hh = 0; hh < 4; ++hh) {
    const int hd = wave * 4 + hh;
    const unsigned short* wp = dtw + (size_t)hd * HIDN + lane * 16;
    float wv[16];
    unpack8(*(const uint4*)wp, wv);
    unpack8(*(const uint4*)(wp + 8), wv + 8);
    float p = 0.f;
#pragma unroll
    for (int i = 0; i < 16; ++i) p += hv[i] * wv[i];
#pragma unroll
    for (int off = 32; off > 0; off >>= 1) p += __shfl_down(p, off);
    if (lane == 0) {
      float z = p + smallf[9312 + hd] + smallf[9296 + hd];
      float dtv = (z > 20.f) ? z : log1pf(expf(z));
      dt_out[l * NH + hd] = dtv;
      A_out[l * NH + hd] = -expf(smallf[9280 + hd]) * dtv;
    }
  }
}

// ---------------- per-head inclusive cumsum over L ----------------
__global__ __launch_bounds__(64) void cumsum_kernel(const float* __restrict__ A_in,
                                                    float* __restrict__ Ac)
{
  const int h = blockIdx.x;
  const int lane = threadIdx.x;
  const int base = lane * 32;
  float run = 0.f;
  for (int i = 0; i < 32; ++i) run += A_in[(base + i) * NH + h];
  float incl = run;
#pragma unroll
  for (int off = 1; off < 64; off <<= 1) {
    float n = __shfl_up(incl, off);
    if (lane >= off) incl += n;
  }
  float r2 = incl - run;
  for (int i = 0; i < 32; ++i) {
    r2 += A_in[(base + i) * NH + h];
    Ac[h * L_SEQ + base + i] = r2;
  }
}

// ---------------- causal depthwise conv K=2 (+ v *= dt), fp16 out ----------
// Q,K channels -> qc [L][3072] fp16 (row-major).
// V channels   -> vt [NH][DHD][L] fp16 (transposed, for the PV MFMA B-operand).
__global__ __launch_bounds__(256) void conv_kernel(
    const float* __restrict__ qkv, const float* __restrict__ smallf,
    const float* __restrict__ dt, unsigned short* __restrict__ qc,
    unsigned short* __restrict__ vt)
{
  const int idx = blockIdx.x * 256 + threadIdx.x;
  const int l = idx / (QKV_N / 4);
  const int c = (idx % (QKV_N / 4)) * 4;
  f4 xc = *(const f4*)&qkv[(size_t)l * QKV_N + c];
  f4 xp = (f4){0.f, 0.f, 0.f, 0.f};
  if (l > 0) xp = *(const f4*)&qkv[(size_t)(l - 1) * QKV_N + c];
  const float* w; const float* b; int cb;
  if (c < HIDN)          { w = smallf;        b = smallf + 2048; cb = c; }
  else if (c < 2 * HIDN) { w = smallf + 3072; b = smallf + 5120; cb = c - HIDN; }
  else                   { w = smallf + 6144; b = smallf + 8192; cb = c - 2 * HIDN; }
  f4 o;
#pragma unroll
  for (int j = 0; j < 4; ++j)
    o[j] = b[cb + j] + xp[j] * w[(cb + j) * 2] + xc[j] * w[(cb + j) * 2 + 1];
  if (c < 2 * HIDN) {
    ushort4 st;
    st.x = f2h(o[0]); st.y = f2h(o[1]); st.z = f2h(o[2]); st.w = f2h(o[3]);
    *(ushort4*)&qc[(size_t)l * QKV_N + c] = st;
  } else {
    const int hh = (c - 2 * HIDN) >> 6;
    const int d0 = (c - 2 * HIDN) & 63;
    o *= dt[l * NH + hh];
    unsigned short* vp = vt + ((size_t)hh * DHD + d0) * L_SEQ + l;
    vp[0]         = f2h(o[0]);
    vp[L_SEQ]     = f2h(o[1]);
    vp[2 * L_SEQ] = f2h(o[2]);
    vp[3 * L_SEQ] = f2h(o[3]);
  }
}

// ---------------- gated causal attention + RMSNorm (MFMA fp16) -------------
// grid (16, NH), 512 threads = 2 groups of 4 waves.
// group0 handles l-tile bx, group1 handles l-tile 31-bx; loop 32-bx iters.
// All MFMA operand access patterns are clones of the verified gemm_bt layout:
//  - QK^T: A = Q rows (regs), B = K rows from row-major [64][68] LDS.
//  - PV:   A = S rows from row-major [64][68] LDS,
//          B = V^T rows (d-major) from row-major [64][68] LDS (staged from vt).
__global__ __launch_bounds__(512) void attn_kernel(
    const unsigned short* __restrict__ qc,     // fp16 [L][3072] (Q,K)
    const unsigned short* __restrict__ vt,     // fp16 [NH][DHD][L] (V^T)
    const float* __restrict__ Ac,              // [NH][L]
    const float* __restrict__ smallf,
    unsigned short* __restrict__ attn_out)     // bf16 [L][1024]
{
  const int h  = blockIdx.y;
  const int bx = blockIdx.x;               // 0..15
  const int t  = threadIdx.x;              // 0..511
  const int grp  = t >> 8;                 // 0/1
  const int tg   = t & 255;
  const int w    = (t >> 6) & 3;           // wave within group
  const int lane = t & 63;
  const int l16  = lane & 15;
  const int quad = lane >> 4;
  const int srow = tg >> 2;                // staging row 0..63
  const int cc   = tg & 3;                 // staging col chunk

  __shared__ __align__(16) unsigned short K_lds[2][64 * 68];  // K[m][d]
  __shared__ __align__(16) unsigned short V_lds[2][64 * 68];  // V^T[d][m]
  __shared__ __align__(16) unsigned short S_lds[2][64 * 68];  // S[l][m]
  unsigned short* Kl = K_lds[grp];
  unsigned short* Vl = V_lds[grp];
  unsigned short* Sl = S_lds[grp];

  const int lt = grp ? (31 - bx) : bx;
  const int l0 = lt * 64;
  const int nIter = 32 - bx;
  const float rc = 1.0f / smallf[9328 + h];
  const float* Acp = Ac + h * L_SEQ;

  // Q A-fragments held in registers: row = l16, k(d) = ks*32 + quad*8 + j
  H8 qf0, qf1;
  {
    const unsigned short* qp =
        qc + (size_t)(l0 + w * 16 + l16) * QKV_N + h * DHD + quad * 8;
    qf0.u4 = *(const uint4*)qp;
    qf1.u4 = *(const uint4*)(qp + 32);
  }
  float alv[4];
#pragma unroll
  for (int r = 0; r < 4; ++r) alv[r] = Acp[l0 + w * 16 + quad * 4 + r];

  f4 acc[4];
#pragma unroll
  for (int i = 0; i < 4; ++i) acc[i] = (f4){0.f, 0.f, 0.f, 0.f};

  // staging pointers: K rows from qc, V^T rows from vt
  const unsigned short* kgp =
      qc + (size_t)srow * QKV_N + HIDN + h * DHD + cc * 16;
  const unsigned short* vgp =
      vt + ((size_t)h * DHD + srow) * L_SEQ + cc * 16;

  // software pipeline: loads for iteration `it` already in flight
  uint4 kA0, kA1, vA0, vA1, kB0, kB1, vB0, vB1;
  kA0 = *(const uint4*)(kgp);  kA1 = *(const uint4*)(kgp + 8);
  vA0 = *(const uint4*)(vgp);  vA1 = *(const uint4*)(vgp + 8);
  kB0 = kA0; kB1 = kA1; vB0 = vA0; vB1 = vA1;

  const int swo = srow * 68 + cc * 16;     // same form for K and V^T tiles

  for (int it = 0; it < nIter; ++it) {
    const int act = (it <= lt);
    const int m0 = it * 64;
    __syncthreads();                              // (a) prev consumers done
    if (act) {
      *(u32x2*)&Kl[swo]      = (u32x2){kA0.x, kA0.y};
      *(u32x2*)&Kl[swo + 4]  = (u32x2){kA0.z, kA0.w};
      *(u32x2*)&Kl[swo + 8]  = (u32x2){kA1.x, kA1.y};
      *(u32x2*)&Kl[swo + 12] = (u32x2){kA1.z, kA1.w};
      *(u32x2*)&Vl[swo]      = (u32x2){vA0.x, vA0.y};
      *(u32x2*)&Vl[swo + 4]  = (u32x2){vA0.z, vA0.w};
      *(u32x2*)&Vl[swo + 8]  = (u32x2){vA1.x, vA1.y};
      *(u32x2*)&Vl[swo + 12] = (u32x2){vA1.z, vA1.w};
    }
    const int itn = it + 1;
    if (itn <= lt) {                              // prefetch next K/V tile
      const unsigned short* kp = kgp + (size_t)itn * 64 * QKV_N;
      const unsigned short* vp = vgp + (size_t)itn * 64;
      kB0 = *(const uint4*)kp; kB1 = *(const uint4*)(kp + 8);
      vB0 = *(const uint4*)vp; vB1 = *(const uint4*)(vp + 8);
    }
    __syncthreads();                              // (b) staging visible
    if (act) {
      // ---- QK^T: S[l][m] ----
      f4 s[4];
#pragma unroll
      for (int i = 0; i < 4; ++i) s[i] = (f4){0.f, 0.f, 0.f, 0.f};
#pragma unroll
      for (int ks = 0; ks < 2; ++ks) {
        H8 qk = ks ? qf1 : qf0;
#pragma unroll
        for (int nt = 0; nt < 4; ++nt) {
          H8 kf;
          const int ko = (nt * 16 + l16) * 68 + ks * 32 + quad * 8;
          kf.u2[0] = *(const u32x2*)&Kl[ko];
          kf.u2[1] = *(const u32x2*)&Kl[ko + 4];
          s[nt] = __builtin_amdgcn_mfma_f32_16x16x32_f16(qk.h, kf.h, s[nt], 0, 0, 0);
        }
      }
      // ---- gate: s * exp(Ac_l - Ac_m) * rc, causal mask; write S fp16 ----
#pragma unroll
      for (int nt = 0; nt < 4; ++nt) {
        const int mg = m0 + nt * 16 + l16;
        const float am = Acp[mg];
#pragma unroll
        for (int r = 0; r < 4; ++r) {
          const int lg = l0 + w * 16 + quad * 4 + r;
          float val = (mg <= lg) ? s[nt][r] * __expf(alv[r] - am) * rc : 0.0f;
          Sl[(w * 16 + quad * 4 + r) * 68 + nt * 16 + l16] = f2h(val);
        }
      }
    }
    __syncthreads();                              // (c) S ready
    if (act) {
      // ---- PV: O[l][d] += S[l][m] * V[m][d]; B-frag from V^T rows ----
#pragma unroll
      for (int ks = 0; ks < 2; ++ks) {
        H8 sa;
        const int so = (w * 16 + l16) * 68 + ks * 32 + quad * 8;
        sa.u2[0] = *(const u32x2*)&Sl[so];
        sa.u2[1] = *(const u32x2*)&Sl[so + 4];
#pragma unroll
        for (int db = 0; db < 4; ++db) {
          H8 vb;
          const int vo = (db * 16 + l16) * 68 + ks * 32 + quad * 8;
          vb.u2[0] = *(const u32x2*)&Vl[vo];
          vb.u2[1] = *(const u32x2*)&Vl[vo + 4];
          acc[db] = __builtin_amdgcn_mfma_f32_16x16x32_f16(sa.h, vb.h, acc[db], 0, 0, 0);
        }
      }
    }
    kA0 = kB0; kA1 = kB1; vA0 = vB0; vA1 = vB1;
  }

  // ---- RMSNorm over d=64 and bf16 store ----
#pragma unroll
  for (int r = 0; r < 4; ++r) {
    float p = acc[0][r] * acc[0][r] + acc[1][r] * acc[1][r]
            + acc[2][r] * acc[2][r] + acc[3][r] * acc[3][r];
#pragma unroll
    for (int off = 1; off < 16; off <<= 1) p += __shfl_xor(p, off);
    const float rn = rsqrtf(p * (1.0f / 64.0f) + 1.1920928955078125e-07f);
    unsigned short* op =
        attn_out + (size_t)(l0 + w * 16 + quad * 4 + r) * HIDN + h * DHD + l16;
#pragma unroll
    for (int ds = 0; ds < 4; ++ds)
      op[ds * 16] = f2b(acc[ds][r] * rn * smallf[9216 + ds * 16 + l16]);
  }
}

extern "C" void kernel_launch(void* const* d_in, const int* in_sizes, int n_in,
                              void* d_out, int out_size, void* d_ws, size_t ws_size,
                              hipStream_t stream)
{
  (void)in_sizes; (void)n_in; (void)out_size; (void)ws_size;
  const void* hs        = d_in[0];
  // d_in[1] = attention_mask: deterministic causal triu — handled analytically
  const void* qkv_w     = d_in[2];
  const void* q_conv_w  = d_in[3];
  const void* q_conv_b  = d_in[4];
  const void* k_conv_w  = d_in[5];
  const void* k_conv_b  = d_in[6];
  const void* v_conv_w  = d_in[7];
  const void* v_conv_b  = d_in[8];
  const void* norm_w    = d_in[9];
  const void* A_log     = d_in[10];
  const void* dt_bias   = d_in[11];
  const void* dt_proj_w = d_in[12];
  const void* dt_proj_b = d_in[13];
  const void* o_w       = d_in[14];
  const void* ordc      = d_in[15];

  char* ws = (char*)d_ws;
  int* flag             = (int*)ws;                              // @0
  unsigned short* hs_b  = (unsigned short*)(ws + 256);           // 2097152*2
  unsigned short* qkvw_b= (unsigned short*)(ws + 4194560);       // 3145728*2
  unsigned short* ow_b  = (unsigned short*)(ws + 10486016);      // 1048576*2
  unsigned short* dtw_b = (unsigned short*)(ws + 12583168);      // 16384*2
  float* smallf         = (float*)(ws + 12615936);               // 9344*4
  float* qkv            = (float*)(ws + 12653568);               // 25165824 (fp32)
  unsigned short* qc_h  = (unsigned short*)(ws + 37819392);      // fp16 12.6MB
  float* dtbuf          = (float*)(ws + 62985216);               // 131072
  float* Abuf           = (float*)(ws + 63116288);               // 131072
  float* Acum           = (float*)(ws + 63247360);               // 131072
  unsigned short* attnb = (unsigned short*)(ws + 63378432);      // 2097152*2
  unsigned short* vt_h  = (unsigned short*)(ws + 67572736);      // 2097152*2 (V^T fp16)

  detect_kernel<<<1, 256, 0, stream>>>((const unsigned short*)hs, flag);
  convert_big<<<(2097152 / 4 + 255) / 256, 256, 0, stream>>>(hs, hs_b, 2097152, flag);
  convert_big<<<(3145728 / 4 + 255) / 256, 256, 0, stream>>>(qkv_w, qkvw_b, 3145728, flag);
  convert_big<<<(1048576 / 4 + 255) / 256, 256, 0, stream>>>(o_w, ow_b, 1048576, flag);
  convert_big<<<(16384 / 4 + 255) / 256, 256, 0, stream>>>(dt_proj_w, dtw_b, 16384, flag);
  convert_small<<<4, 256, 0, stream>>>(q_conv_w, q_conv_b, k_conv_w, k_conv_b,
                                       v_conv_w, v_conv_b, norm_w, A_log,
                                       dt_bias, dt_proj_b, ordc, smallf, flag);

  gemm_bt<0><<<dim3(QKV_N / 64, L_SEQ / 64), 256, 0, stream>>>(
      hs_b, qkvw_b, qkv, L_SEQ, QKV_N, HIDN, flag);
  dt_kernel<<<L_SEQ, 256, 0, stream>>>(hs_b, dtw_b, smallf, dtbuf, Abuf);
  cumsum_kernel<<<NH, 64, 0, stream>>>(Abuf, Acum);
  conv_kernel<<<(L_SEQ * QKV_N / 4) / 256, 256, 0, stream>>>(qkv, smallf, dtbuf, qc_h, vt_h);
  attn_kernel<<<dim3(16, NH), 512, 0, stream>>>(qc_h, vt_h, Acum, smallf, attnb);
  gemm_bt<1><<<dim3(HIDN / 64, L_SEQ / 64), 256, 0, stream>>>(
      attnb, ow_b, d_out, L_SEQ, HIDN, HIDN, flag);
}

// Round 5
// 270.733 us; speedup vs baseline: 4.4321x; 1.0334x over previous
//
#include <hip/hip_runtime.h>
#include <hip/hip_bf16.h>

#define L_SEQ 2048
#define HIDN  1024
#define NH    16
#define DHD   64
#define QKV_N 3072

typedef float f4 __attribute__((ext_vector_type(4)));
typedef __bf16 bf16x8 __attribute__((ext_vector_type(8)));
typedef _Float16 half8 __attribute__((ext_vector_type(8)));
typedef unsigned int u32x2 __attribute__((ext_vector_type(2)));

union H8 {
  half8 h;
  u32x2 u2[2];
  uint4 u4;
};

__device__ __forceinline__ float b2f(unsigned short u) {
  union { unsigned int i; float f; } c; c.i = ((unsigned int)u) << 16; return c.f;
}
__device__ __forceinline__ unsigned short f2b(float f) {
  union { float f; unsigned int i; } c; c.f = f;
  unsigned int r = c.i + 0x7FFFu + ((c.i >> 16) & 1u);
  return (unsigned short)(r >> 16);
}
__device__ __forceinline__ unsigned short f2h(float f) {
  union { _Float16 h; unsigned short u; } c; c.h = (_Float16)f; return c.u;
}
__device__ __forceinline__ void unpack8(uint4 u, float* f) {
  unsigned int w[4] = {u.x, u.y, u.z, u.w};
#pragma unroll
  for (int i = 0; i < 4; ++i) {
    union { unsigned int i_; float f_; } lo, hi;
    lo.i_ = w[i] << 16;
    hi.i_ = w[i] & 0xffff0000u;
    f[2 * i] = lo.f_; f[2 * i + 1] = hi.f_;
  }
}

// ---------------- runtime input-dtype detection ----------------
__global__ void detect_kernel(const unsigned short* __restrict__ hs, int* flag) {
  __shared__ int cnt;
  if (threadIdx.x == 0) cnt = 0;
  __syncthreads();
  int c = 0;
  for (int i = threadIdx.x; i < 8192; i += 256) {
    unsigned int e = (hs[i] >> 7) & 0xFFu;
    if (e >= 140u) c++;
  }
  atomicAdd(&cnt, c);
  __syncthreads();
  if (threadIdx.x == 0) *flag = (cnt >= 32) ? 1 : 0;  // 1 = fp32 inputs
}

// ---------------- canonicalize big arrays to bf16 ----------------
__global__ __launch_bounds__(256) void convert_big(const void* __restrict__ in,
                                                   unsigned short* __restrict__ out,
                                                   int n, const int* __restrict__ flag) {
  const int i = (blockIdx.x * 256 + threadIdx.x) * 4;
  if (i >= n) return;
  if (*flag) {
    f4 v = *(const f4*)((const float*)in + i);
    ushort4 o;
    o.x = f2b(v[0]); o.y = f2b(v[1]); o.z = f2b(v[2]); o.w = f2b(v[3]);
    *(ushort4*)(out + i) = o;
  } else {
    *(uint2*)(out + i) = *(const uint2*)((const unsigned short*)in + i);
  }
}

// ---------------- canonicalize small arrays to fp32 ----------------
// layout in smallf: qw@0(2048) qb@2048(1024) kw@3072(2048) kb@5120(1024)
// vw@6144(2048) vb@8192(1024) nw@9216(64) al@9280(16) dt_bias@9296(16)
// dt_proj_b@9312(16) oc@9328(16)  total 9344
__global__ __launch_bounds__(256) void convert_small(
    const void* qw, const void* qb, const void* kw, const void* kb,
    const void* vw, const void* vb, const void* nw, const void* al,
    const void* dtb, const void* dpb, const void* oc,
    float* __restrict__ out, const int* __restrict__ flag) {
  const int f = *flag;
  const void* ptrs[11] = {qw, qb, kw, kb, vw, vb, nw, al, dtb, dpb, oc};
  const int sizes[11] = {2048, 1024, 2048, 1024, 2048, 1024, 64, 16, 16, 16, 16};
  int off = 0;
  for (int a = 0; a < 11; ++a) {
    for (int i = threadIdx.x + blockIdx.x * 256; i < sizes[a]; i += gridDim.x * 256)
      out[off + i] = f ? ((const float*)ptrs[a])[i] : b2f(((const unsigned short*)ptrs[a])[i]);
    off += sizes[a];
  }
}

// ---------------- C = A (MxK) * B^T (NxK), bf16 in, fp32 acc ----------------
template <int MODE>
__global__ __launch_bounds__(256) void gemm_bt(
    const unsigned short* __restrict__ A, const unsigned short* __restrict__ B,
    void* __restrict__ Cv, int M, int N, int K, const int* __restrict__ flag)
{
  __shared__ __align__(16) short As[64 * 40];
  __shared__ __align__(16) short Bs[64 * 40];
  const int t = threadIdx.x;
  const int wave = t >> 6, lane = t & 63;
  const int quad = lane >> 4, l16 = lane & 15;
  const int m0 = blockIdx.y * 64, n0 = blockIdx.x * 64;
  const int srow = t >> 2, scol = (t & 3) * 8;
  f4 acc[4];
#pragma unroll
  for (int i = 0; i < 4; ++i) acc[i] = (f4){0.f, 0.f, 0.f, 0.f};
  const unsigned short* ap = A + (size_t)(m0 + srow) * K + scol;
  const unsigned short* bp = B + (size_t)(n0 + srow) * K + scol;
  for (int k0 = 0; k0 < K; k0 += 32) {
    uint4 av = *(const uint4*)(ap + k0);
    uint4 bv = *(const uint4*)(bp + k0);
    __syncthreads();
    *(uint4*)&As[srow * 40 + scol] = av;
    *(uint4*)&Bs[srow * 40 + scol] = bv;
    __syncthreads();
    bf16x8 af = *(const bf16x8*)&As[(wave * 16 + l16) * 40 + quad * 8];
#pragma unroll
    for (int nt = 0; nt < 4; ++nt) {
      bf16x8 bf = *(const bf16x8*)&Bs[(nt * 16 + l16) * 40 + quad * 8];
      acc[nt] = __builtin_amdgcn_mfma_f32_16x16x32_bf16(af, bf, acc[nt], 0, 0, 0);
    }
  }
  const int outf32 = (MODE == 0) ? 1 : (*flag ? 1 : 0);
#pragma unroll
  for (int nt = 0; nt < 4; ++nt) {
#pragma unroll
    for (int r = 0; r < 4; ++r) {
      int m = m0 + wave * 16 + quad * 4 + r;
      int n = n0 + nt * 16 + l16;
      if (outf32) ((float*)Cv)[(size_t)m * N + n] = acc[nt][r];
      else        ((unsigned short*)Cv)[(size_t)m * N + n] = f2b(acc[nt][r]);
    }
  }
}

// ---------------- dt = softplus(hs @ dtw^T + dt_proj_b + dt_bias) ----------
__global__ __launch_bounds__(256) void dt_kernel(
    const unsigned short* __restrict__ hs,
    const unsigned short* __restrict__ dtw,
    const float* __restrict__ smallf,
    float* __restrict__ dt_out, float* __restrict__ A_out)
{
  const int l = blockIdx.x;
  const int t = threadIdx.x, wave = t >> 6, lane = t & 63;
  const unsigned short* hp = hs + (size_t)l * HIDN + lane * 16;
  float hv[16];
  unpack8(*(const uint4*)hp, hv);
  unpack8(*(const uint4*)(hp + 8), hv + 8);
#pragma unroll
  for (int hh = 0; hh < 4; ++hh) {
    const int hd = wave * 4 + hh;
    const unsigned short* wp = dtw + (size_t)hd * HIDN + lane * 16;
    float wv[16];
    unpack8(*(const uint4*)wp, wv);
    unpack8(*(const uint4*)(wp + 8), wv + 8);
    float p = 0.f;
#pragma unroll
    for (int i = 0; i < 16; ++i) p += hv[i] * wv[i];
#pragma unroll
    for (int off = 32; off > 0; off >>= 1) p += __shfl_down(p, off);
    if (lane == 0) {
      float z = p + smallf[9312 + hd] + smallf[9296 + hd];
      float dtv = (z > 20.f) ? z : log1pf(expf(z));
      dt_out[l * NH + hd] = dtv;
      A_out[l * NH + hd] = -expf(smallf[9280 + hd]) * dtv;
    }
  }
}

// ---------------- per-head inclusive cumsum over L ----------------
__global__ __launch_bounds__(64) void cumsum_kernel(const float* __restrict__ A_in,
                                                    float* __restrict__ Ac)
{
  const int h = blockIdx.x;
  const int lane = threadIdx.x;
  const int base = lane * 32;
  float run = 0.f;
  for (int i = 0; i < 32; ++i) run += A_in[(base + i) * NH + h];
  float incl = run;
#pragma unroll
  for (int off = 1; off < 64; off <<= 1) {
    float n = __shfl_up(incl, off);
    if (lane >= off) incl += n;
  }
  float r2 = incl - run;
  for (int i = 0; i < 32; ++i) {
    r2 += A_in[(base + i) * NH + h];
    Ac[h * L_SEQ + base + i] = r2;
  }
}

// ---------------- causal depthwise conv K=2 (+ v *= dt), fp16 out ----------
// All QKV channels -> qc [L][3072] fp16 (row-major, fully coalesced).
__global__ __launch_bounds__(256) void conv_kernel(
    const float* __restrict__ qkv, const float* __restrict__ smallf,
    const float* __restrict__ dt, unsigned short* __restrict__ qc)
{
  const int idx = blockIdx.x * 256 + threadIdx.x;
  const int l = idx / (QKV_N / 4);
  const int c = (idx % (QKV_N / 4)) * 4;
  f4 xc = *(const f4*)&qkv[(size_t)l * QKV_N + c];
  f4 xp = (f4){0.f, 0.f, 0.f, 0.f};
  if (l > 0) xp = *(const f4*)&qkv[(size_t)(l - 1) * QKV_N + c];
  const float* w; const float* b; int cb;
  if (c < HIDN)          { w = smallf;        b = smallf + 2048; cb = c; }
  else if (c < 2 * HIDN) { w = smallf + 3072; b = smallf + 5120; cb = c - HIDN; }
  else                   { w = smallf + 6144; b = smallf + 8192; cb = c - 2 * HIDN; }
  f4 o;
#pragma unroll
  for (int j = 0; j < 4; ++j)
    o[j] = b[cb + j] + xp[j] * w[(cb + j) * 2] + xc[j] * w[(cb + j) * 2 + 1];
  if (c >= 2 * HIDN) {
    const int hh = (c - 2 * HIDN) >> 6;
    o *= dt[l * NH + hh];
  }
  ushort4 st;
  st.x = f2h(o[0]); st.y = f2h(o[1]); st.z = f2h(o[2]); st.w = f2h(o[3]);
  *(ushort4*)&qc[(size_t)l * QKV_N + c] = st;
}

// ---------------- V transpose: qc V-part -> vt [NH][DHD][L] (LDS-tiled) ----
__global__ __launch_bounds__(256) void transpose_v(
    const unsigned short* __restrict__ qc, unsigned short* __restrict__ vt)
{
  const int h = blockIdx.y;
  const int l0 = blockIdx.x * 64;
  const int t = threadIdx.x;
  const int srow = t >> 2, cc = t & 3;
  __shared__ __align__(16) unsigned short Ts[64 * 68];
  const unsigned short* gp =
      qc + (size_t)(l0 + srow) * QKV_N + 2 * HIDN + h * DHD + cc * 16;
  uint4 a = *(const uint4*)gp;
  uint4 b = *(const uint4*)(gp + 8);
  *(uint4*)&Ts[srow * 68 + cc * 16] = a;
  *(uint4*)&Ts[srow * 68 + cc * 16 + 8] = b;
  __syncthreads();
  __align__(16) unsigned short o[16];
#pragma unroll
  for (int j = 0; j < 16; ++j) o[j] = Ts[(cc * 16 + j) * 68 + srow];
  unsigned short* op = vt + ((size_t)h * DHD + srow) * L_SEQ + l0 + cc * 16;
  *(uint4*)op = *(const uint4*)&o[0];
  *(uint4*)(op + 8) = *(const uint4*)&o[8];
}

// ---------------- gated causal attention + RMSNorm (MFMA fp16) -------------
// grid (32, NH), 256 threads = 4 waves, one 64-row l-tile per block.
// lt = 31 - blockIdx.x (heavy blocks dispatch first for load balance).
// K/V double-buffered in LDS -> ONE barrier per kv-iteration.
// S roundtrip is wave-private (wave w writes AND reads rows w*16..w*16+15),
// so no barrier is needed between the gate and PV (same-wave LDS RAW).
__global__ __launch_bounds__(256) void attn_kernel(
    const unsigned short* __restrict__ qc,     // fp16 [L][3072] (Q,K,V)
    const unsigned short* __restrict__ vt,     // fp16 [NH][DHD][L] (V^T)
    const float* __restrict__ Ac,              // [NH][L]
    const float* __restrict__ smallf,
    unsigned short* __restrict__ attn_out)     // bf16 [L][1024]
{
  const int h  = blockIdx.y;
  const int lt = 31 - blockIdx.x;
  const int t  = threadIdx.x;              // 0..255
  const int w    = t >> 6;                 // wave 0..3
  const int lane = t & 63;
  const int l16  = lane & 15;
  const int quad = lane >> 4;
  const int srow = t >> 2;                 // staging row 0..63
  const int cc   = t & 3;                  // staging col chunk

  __shared__ __align__(16) unsigned short K_lds[2][64 * 68];  // K[m][d]
  __shared__ __align__(16) unsigned short V_lds[2][64 * 68];  // V^T[d][m]
  __shared__ __align__(16) unsigned short S_lds[64 * 68];     // S[l][m]

  const int l0 = lt * 64;
  const float rc = 1.0f / smallf[9328 + h];
  const float* Acp = Ac + h * L_SEQ;

  // Q A-fragments held in registers: row = l16, k(d) = ks*32 + quad*8 + j
  H8 qf0, qf1;
  {
    const unsigned short* qp =
        qc + (size_t)(l0 + w * 16 + l16) * QKV_N + h * DHD + quad * 8;
    qf0.u4 = *(const uint4*)qp;
    qf1.u4 = *(const uint4*)(qp + 32);
  }
  float alv[4];
#pragma unroll
  for (int r = 0; r < 4; ++r) alv[r] = Acp[l0 + w * 16 + quad * 4 + r];

  f4 acc[4];
#pragma unroll
  for (int i = 0; i < 4; ++i) acc[i] = (f4){0.f, 0.f, 0.f, 0.f};

  const unsigned short* kgp =
      qc + (size_t)srow * QKV_N + HIDN + h * DHD + cc * 16;
  const unsigned short* vgp =
      vt + ((size_t)h * DHD + srow) * L_SEQ + cc * 16;

  const int swo = srow * 68 + cc * 16;

  // prologue: tile 0 in registers
  uint4 k0v = *(const uint4*)kgp,       k1v = *(const uint4*)(kgp + 8);
  uint4 v0v = *(const uint4*)vgp,       v1v = *(const uint4*)(vgp + 8);

  int cur = 0;
  for (int it = 0; it <= lt; ++it) {
    unsigned short* Kl = K_lds[cur];
    unsigned short* Vl = V_lds[cur];
    // stage current tile (WAR-safe: buf[cur] last read in iter it-2)
    *(u32x2*)&Kl[swo]      = (u32x2){k0v.x, k0v.y};
    *(u32x2*)&Kl[swo + 4]  = (u32x2){k0v.z, k0v.w};
    *(u32x2*)&Kl[swo + 8]  = (u32x2){k1v.x, k1v.y};
    *(u32x2*)&Kl[swo + 12] = (u32x2){k1v.z, k1v.w};
    *(u32x2*)&Vl[swo]      = (u32x2){v0v.x, v0v.y};
    *(u32x2*)&Vl[swo + 4]  = (u32x2){v0v.z, v0v.w};
    *(u32x2*)&Vl[swo + 8]  = (u32x2){v1v.x, v1v.y};
    *(u32x2*)&Vl[swo + 12] = (u32x2){v1v.z, v1v.w};
    if (it < lt) {                                // prefetch next tile
      const unsigned short* kp = kgp + (size_t)(it + 1) * 64 * QKV_N;
      const unsigned short* vp = vgp + (size_t)(it + 1) * 64;
      k0v = *(const uint4*)kp; k1v = *(const uint4*)(kp + 8);
      v0v = *(const uint4*)vp; v1v = *(const uint4*)(vp + 8);
    }
    __syncthreads();                              // staging visible

    // ---- QK^T: S[l][m] ----
    f4 s[4];
#pragma unroll
    for (int i = 0; i < 4; ++i) s[i] = (f4){0.f, 0.f, 0.f, 0.f};
#pragma unroll
    for (int ks = 0; ks < 2; ++ks) {
      H8 qk = ks ? qf1 : qf0;
#pragma unroll
      for (int nt = 0; nt < 4; ++nt) {
        H8 kf;
        const int ko = (nt * 16 + l16) * 68 + ks * 32 + quad * 8;
        kf.u2[0] = *(const u32x2*)&K_lds[cur][ko];
        kf.u2[1] = *(const u32x2*)&K_lds[cur][ko + 4];
        s[nt] = __builtin_amdgcn_mfma_f32_16x16x32_f16(qk.h, kf.h, s[nt], 0, 0, 0);
      }
    }
    // ---- gate: s * exp(Ac_l - Ac_m) * rc, causal mask; write S fp16 ----
    const int m0 = it * 64;
#pragma unroll
    for (int nt = 0; nt < 4; ++nt) {
      const int mg = m0 + nt * 16 + l16;
      const float am = Acp[mg];
#pragma unroll
      for (int r = 0; r < 4; ++r) {
        const int lg = l0 + w * 16 + quad * 4 + r;
        float val = (mg <= lg) ? s[nt][r] * __expf(alv[r] - am) * rc : 0.0f;
        S_lds[(w * 16 + quad * 4 + r) * 68 + nt * 16 + l16] = f2h(val);
      }
    }
    // ---- PV: O[l][d] += S[l][m] * V[m][d] (wave-private S rows) ----
#pragma unroll
    for (int ks = 0; ks < 2; ++ks) {
      H8 sa;
      const int so = (w * 16 + l16) * 68 + ks * 32 + quad * 8;
      sa.u2[0] = *(const u32x2*)&S_lds[so];
      sa.u2[1] = *(const u32x2*)&S_lds[so + 4];
#pragma unroll
      for (int db = 0; db < 4; ++db) {
        H8 vb;
        const int vo = (db * 16 + l16) * 68 + ks * 32 + quad * 8;
        vb.u2[0] = *(const u32x2*)&V_lds[cur][vo];
        vb.u2[1] = *(const u32x2*)&V_lds[cur][vo + 4];
        acc[db] = __builtin_amdgcn_mfma_f32_16x16x32_f16(sa.h, vb.h, acc[db], 0, 0, 0);
      }
    }
    cur ^= 1;
  }

  // ---- RMSNorm over d=64 and bf16 store ----
#pragma unroll
  for (int r = 0; r < 4; ++r) {
    float p = acc[0][r] * acc[0][r] + acc[1][r] * acc[1][r]
            + acc[2][r] * acc[2][r] + acc[3][r] * acc[3][r];
#pragma unroll
    for (int off = 1; off < 16; off <<= 1) p += __shfl_xor(p, off);
    const float rn = rsqrtf(p * (1.0f / 64.0f) + 1.1920928955078125e-07f);
    unsigned short* op =
        attn_out + (size_t)(l0 + w * 16 + quad * 4 + r) * HIDN + h * DHD + l16;
#pragma unroll
    for (int ds = 0; ds < 4; ++ds)
      op[ds * 16] = f2b(acc[ds][r] * rn * smallf[9216 + ds * 16 + l16]);
  }
}

extern "C" void kernel_launch(void* const* d_in, const int* in_sizes, int n_in,
                              void* d_out, int out_size, void* d_ws, size_t ws_size,
                              hipStream_t stream)
{
  (void)in_sizes; (void)n_in; (void)out_size; (void)ws_size;
  const void* hs        = d_in[0];
  // d_in[1] = attention_mask: deterministic causal triu — handled analytically
  const void* qkv_w     = d_in[2];
  const void* q_conv_w  = d_in[3];
  const void* q_conv_b  = d_in[4];
  const void* k_conv_w  = d_in[5];
  const void* k_conv_b  = d_in[6];
  const void* v_conv_w  = d_in[7];
  const void* v_conv_b  = d_in[8];
  const void* norm_w    = d_in[9];
  const void* A_log     = d_in[10];
  const void* dt_bias   = d_in[11];
  const void* dt_proj_w = d_in[12];
  const void* dt_proj_b = d_in[13];
  const void* o_w       = d_in[14];
  const void* ordc      = d_in[15];

  char* ws = (char*)d_ws;
  int* flag             = (int*)ws;                              // @0
  unsigned short* hs_b  = (unsigned short*)(ws + 256);           // 2097152*2
  unsigned short* qkvw_b= (unsigned short*)(ws + 4194560);       // 3145728*2
  unsigned short* ow_b  = (unsigned short*)(ws + 10486016);      // 1048576*2
  unsigned short* dtw_b = (unsigned short*)(ws + 12583168);      // 16384*2
  float* smallf         = (float*)(ws + 12615936);               // 9344*4
  float* qkv            = (float*)(ws + 12653568);               // 25165824 (fp32)
  unsigned short* qc_h  = (unsigned short*)(ws + 37819392);      // fp16 12.6MB
  float* dtbuf          = (float*)(ws + 62985216);               // 131072
  float* Abuf           = (float*)(ws + 63116288);               // 131072
  float* Acum           = (float*)(ws + 63247360);               // 131072
  unsigned short* attnb = (unsigned short*)(ws + 63378432);      // 2097152*2
  unsigned short* vt_h  = (unsigned short*)(ws + 67572736);      // 2097152*2 (V^T fp16)

  detect_kernel<<<1, 256, 0, stream>>>((const unsigned short*)hs, flag);
  convert_big<<<(2097152 / 4 + 255) / 256, 256, 0, stream>>>(hs, hs_b, 2097152, flag);
  convert_big<<<(3145728 / 4 + 255) / 256, 256, 0, stream>>>(qkv_w, qkvw_b, 3145728, flag);
  convert_big<<<(1048576 / 4 + 255) / 256, 256, 0, stream>>>(o_w, ow_b, 1048576, flag);
  convert_big<<<(16384 / 4 + 255) / 256, 256, 0, stream>>>(dt_proj_w, dtw_b, 16384, flag);
  convert_small<<<4, 256, 0, stream>>>(q_conv_w, q_conv_b, k_conv_w, k_conv_b,
                                       v_conv_w, v_conv_b, norm_w, A_log,
                                       dt_bias, dt_proj_b, ordc, smallf, flag);

  gemm_bt<0><<<dim3(QKV_N / 64, L_SEQ / 64), 256, 0, stream>>>(
      hs_b, qkvw_b, qkv, L_SEQ, QKV_N, HIDN, flag);
  dt_kernel<<<L_SEQ, 256, 0, stream>>>(hs_b, dtw_b, smallf, dtbuf, Abuf);
  cumsum_kernel<<<NH, 64, 0, stream>>>(Abuf, Acum);
  conv_kernel<<<(L_SEQ * QKV_N / 4) / 256, 256, 0, stream>>>(qkv, smallf, dtbuf, qc_h);
  transpose_v<<<dim3(L_SEQ / 64, NH), 256, 0, stream>>>(qc_h, vt_h);
  attn_kernel<<<dim3(32, NH), 256, 0, stream>>>(qc_h, vt_h, Acum, smallf, attnb);
  gemm_bt<1><<<dim3(HIDN / 64, L_SEQ / 64), 256, 0, stream>>>(
      attnb, ow_b, d_out, L_SEQ, HIDN, HIDN, flag);
}

// Round 6
// 257.100 us; speedup vs baseline: 4.6671x; 1.0530x over previous
//
#include <hip/hip_runtime.h>
#include <hip/hip_bf16.h>

#define L_SEQ 2048
#define HIDN  1024
#define NH    16
#define DHD   64
#define QKV_N 3072

typedef float f4 __attribute__((ext_vector_type(4)));
typedef __bf16 bf16x8 __attribute__((ext_vector_type(8)));
typedef _Float16 half8 __attribute__((ext_vector_type(8)));
typedef unsigned int u32x2 __attribute__((ext_vector_type(2)));

union H8 {
  half8 h;
  u32x2 u2[2];
  uint4 u4;
};

__device__ __forceinline__ float b2f(unsigned short u) {
  union { unsigned int i; float f; } c; c.i = ((unsigned int)u) << 16; return c.f;
}
__device__ __forceinline__ unsigned short f2b(float f) {
  union { float f; unsigned int i; } c; c.f = f;
  unsigned int r = c.i + 0x7FFFu + ((c.i >> 16) & 1u);
  return (unsigned short)(r >> 16);
}
__device__ __forceinline__ unsigned short f2h(float f) {
  union { _Float16 h; unsigned short u; } c; c.h = (_Float16)f; return c.u;
}
__device__ __forceinline__ void unpack8(uint4 u, float* f) {
  unsigned int w[4] = {u.x, u.y, u.z, u.w};
#pragma unroll
  for (int i = 0; i < 4; ++i) {
    union { unsigned int i_; float f_; } lo, hi;
    lo.i_ = w[i] << 16;
    hi.i_ = w[i] & 0xffff0000u;
    f[2 * i] = lo.f_; f[2 * i + 1] = hi.f_;
  }
}

// ---------------- runtime input-dtype detection ----------------
__global__ void detect_kernel(const unsigned short* __restrict__ hs, int* flag) {
  __shared__ int cnt;
  if (threadIdx.x == 0) cnt = 0;
  __syncthreads();
  int c = 0;
  for (int i = threadIdx.x; i < 8192; i += 256) {
    unsigned int e = (hs[i] >> 7) & 0xFFu;
    if (e >= 140u) c++;
  }
  atomicAdd(&cnt, c);
  __syncthreads();
  if (threadIdx.x == 0) *flag = (cnt >= 32) ? 1 : 0;  // 1 = fp32 inputs
}

// ---------------- canonicalize big arrays to bf16 ----------------
__global__ __launch_bounds__(256) void convert_big(const void* __restrict__ in,
                                                   unsigned short* __restrict__ out,
                                                   int n, const int* __restrict__ flag) {
  const int i = (blockIdx.x * 256 + threadIdx.x) * 4;
  if (i >= n) return;
  if (*flag) {
    f4 v = *(const f4*)((const float*)in + i);
    ushort4 o;
    o.x = f2b(v[0]); o.y = f2b(v[1]); o.z = f2b(v[2]); o.w = f2b(v[3]);
    *(ushort4*)(out + i) = o;
  } else {
    *(uint2*)(out + i) = *(const uint2*)((const unsigned short*)in + i);
  }
}

// ---------------- canonicalize small arrays to fp32 ----------------
// layout in smallf: qw@0(2048) qb@2048(1024) kw@3072(2048) kb@5120(1024)
// vw@6144(2048) vb@8192(1024) nw@9216(64) al@9280(16) dt_bias@9296(16)
// dt_proj_b@9312(16) oc@9328(16)  total 9344
__global__ __launch_bounds__(256) void convert_small(
    const void* qw, const void* qb, const void* kw, const void* kb,
    const void* vw, const void* vb, const void* nw, const void* al,
    const void* dtb, const void* dpb, const void* oc,
    float* __restrict__ out, const int* __restrict__ flag) {
  const int f = *flag;
  const void* ptrs[11] = {qw, qb, kw, kb, vw, vb, nw, al, dtb, dpb, oc};
  const int sizes[11] = {2048, 1024, 2048, 1024, 2048, 1024, 64, 16, 16, 16, 16};
  int off = 0;
  for (int a = 0; a < 11; ++a) {
    for (int i = threadIdx.x + blockIdx.x * 256; i < sizes[a]; i += gridDim.x * 256)
      out[off + i] = f ? ((const float*)ptrs[a])[i] : b2f(((const unsigned short*)ptrs[a])[i]);
    off += sizes[a];
  }
}

// ------- C = A (MxK) * B^T (NxK), bf16 in, fp32 out, 128x128 tile ---------
// 256 threads = 4 waves (2x2), each wave owns a 64x64 sub-tile (4x4 frags).
__global__ __launch_bounds__(256) void gemm128(
    const unsigned short* __restrict__ A, const unsigned short* __restrict__ B,
    float* __restrict__ C, int M, int N, int K)
{
  __shared__ __align__(16) unsigned short As[128 * 40];
  __shared__ __align__(16) unsigned short Bs[128 * 40];
  const int t = threadIdx.x;
  const int w = t >> 6, lane = t & 63;
  const int quad = lane >> 4, l16 = lane & 15;
  const int wr = w >> 1, wc = w & 1;
  const int m0 = blockIdx.y * 128, n0 = blockIdx.x * 128;
  const int srow = t >> 1;             // 0..127
  const int scol = (t & 1) * 16;       // elements (16B chunk pair)

  f4 acc[4][4];
#pragma unroll
  for (int i = 0; i < 4; ++i)
#pragma unroll
    for (int j = 0; j < 4; ++j) acc[i][j] = (f4){0.f, 0.f, 0.f, 0.f};

  const unsigned short* apg = A + (size_t)(m0 + srow) * K + scol;
  const unsigned short* bpg = B + (size_t)(n0 + srow) * K + scol;
  uint4 a0 = *(const uint4*)apg,       a1 = *(const uint4*)(apg + 8);
  uint4 b0 = *(const uint4*)bpg,       b1 = *(const uint4*)(bpg + 8);

  for (int k0 = 0; k0 < K; k0 += 32) {
    __syncthreads();                       // WAR: prev compute done
    *(uint4*)&As[srow * 40 + scol]     = a0;
    *(uint4*)&As[srow * 40 + scol + 8] = a1;
    *(uint4*)&Bs[srow * 40 + scol]     = b0;
    *(uint4*)&Bs[srow * 40 + scol + 8] = b1;
    __syncthreads();                       // staging visible
    if (k0 + 32 < K) {                     // prefetch next K-tile (overlaps MFMA)
      a0 = *(const uint4*)(apg + k0 + 32); a1 = *(const uint4*)(apg + k0 + 40);
      b0 = *(const uint4*)(bpg + k0 + 32); b1 = *(const uint4*)(bpg + k0 + 40);
    }
    bf16x8 aF[4], bF[4];
#pragma unroll
    for (int i = 0; i < 4; ++i)
      aF[i] = *(const bf16x8*)&As[(wr * 64 + i * 16 + l16) * 40 + quad * 8];
#pragma unroll
    for (int j = 0; j < 4; ++j)
      bF[j] = *(const bf16x8*)&Bs[(wc * 64 + j * 16 + l16) * 40 + quad * 8];
#pragma unroll
    for (int i = 0; i < 4; ++i)
#pragma unroll
      for (int j = 0; j < 4; ++j)
        acc[i][j] = __builtin_amdgcn_mfma_f32_16x16x32_bf16(aF[i], bF[j], acc[i][j], 0, 0, 0);
  }

#pragma unroll
  for (int i = 0; i < 4; ++i)
#pragma unroll
    for (int j = 0; j < 4; ++j)
#pragma unroll
      for (int r = 0; r < 4; ++r) {
        int m = m0 + wr * 64 + i * 16 + quad * 4 + r;
        int n = n0 + wc * 64 + j * 16 + l16;
        C[(size_t)m * N + n] = acc[i][j][r];
      }
}

// ---------------- C = A (MxK) * B^T (NxK), bf16 in, fp32 acc ----------------
template <int MODE>
__global__ __launch_bounds__(256) void gemm_bt(
    const unsigned short* __restrict__ A, const unsigned short* __restrict__ B,
    void* __restrict__ Cv, int M, int N, int K, const int* __restrict__ flag)
{
  __shared__ __align__(16) short As[64 * 40];
  __shared__ __align__(16) short Bs[64 * 40];
  const int t = threadIdx.x;
  const int wave = t >> 6, lane = t & 63;
  const int quad = lane >> 4, l16 = lane & 15;
  const int m0 = blockIdx.y * 64, n0 = blockIdx.x * 64;
  const int srow = t >> 2, scol = (t & 3) * 8;
  f4 acc[4];
#pragma unroll
  for (int i = 0; i < 4; ++i) acc[i] = (f4){0.f, 0.f, 0.f, 0.f};
  const unsigned short* ap = A + (size_t)(m0 + srow) * K + scol;
  const unsigned short* bp = B + (size_t)(n0 + srow) * K + scol;
  for (int k0 = 0; k0 < K; k0 += 32) {
    uint4 av = *(const uint4*)(ap + k0);
    uint4 bv = *(const uint4*)(bp + k0);
    __syncthreads();
    *(uint4*)&As[srow * 40 + scol] = av;
    *(uint4*)&Bs[srow * 40 + scol] = bv;
    __syncthreads();
    bf16x8 af = *(const bf16x8*)&As[(wave * 16 + l16) * 40 + quad * 8];
#pragma unroll
    for (int nt = 0; nt < 4; ++nt) {
      bf16x8 bf = *(const bf16x8*)&Bs[(nt * 16 + l16) * 40 + quad * 8];
      acc[nt] = __builtin_amdgcn_mfma_f32_16x16x32_bf16(af, bf, acc[nt], 0, 0, 0);
    }
  }
  const int outf32 = (MODE == 0) ? 1 : (*flag ? 1 : 0);
#pragma unroll
  for (int nt = 0; nt < 4; ++nt) {
#pragma unroll
    for (int r = 0; r < 4; ++r) {
      int m = m0 + wave * 16 + quad * 4 + r;
      int n = n0 + nt * 16 + l16;
      if (outf32) ((float*)Cv)[(size_t)m * N + n] = acc[nt][r];
      else        ((unsigned short*)Cv)[(size_t)m * N + n] = f2b(acc[nt][r]);
    }
  }
}

// ---------------- dt = softplus(hs @ dtw^T + dt_proj_b + dt_bias) ----------
__global__ __launch_bounds__(256) void dt_kernel(
    const unsigned short* __restrict__ hs,
    const unsigned short* __restrict__ dtw,
    const float* __restrict__ smallf,
    float* __restrict__ dt_out, float* __restrict__ A_out)
{
  const int l = blockIdx.x;
  const int t = threadIdx.x, wave = t >> 6, lane = t & 63;
  const unsigned short* hp = hs + (size_t)l * HIDN + lane * 16;
  float hv[16];
  unpack8(*(const uint4*)hp, hv);
  unpack8(*(const uint4*)(hp + 8), hv + 8);
#pragma unroll
  for (int hh = 0; hh < 4; ++hh) {
    const int hd = wave * 4 + hh;
    const unsigned short* wp = dtw + (size_t)hd * HIDN + lane * 16;
    float wv[16];
    unpack8(*(const uint4*)wp, wv);
    unpack8(*(const uint4*)(wp + 8), wv + 8);
    float p = 0.f;
#pragma unroll
    for (int i = 0; i < 16; ++i) p += hv[i] * wv[i];
#pragma unroll
    for (int off = 32; off > 0; off >>= 1) p += __shfl_down(p, off);
    if (lane == 0) {
      float z = p + smallf[9312 + hd] + smallf[9296 + hd];
      float dtv = (z > 20.f) ? z : log1pf(expf(z));
      dt_out[l * NH + hd] = dtv;
      A_out[l * NH + hd] = -expf(smallf[9280 + hd]) * dtv;
    }
  }
}

// ---------------- per-head inclusive cumsum over L ----------------
__global__ __launch_bounds__(64) void cumsum_kernel(const float* __restrict__ A_in,
                                                    float* __restrict__ Ac)
{
  const int h = blockIdx.x;
  const int lane = threadIdx.x;
  const int base = lane * 32;
  float run = 0.f;
  for (int i = 0; i < 32; ++i) run += A_in[(base + i) * NH + h];
  float incl = run;
#pragma unroll
  for (int off = 1; off < 64; off <<= 1) {
    float n = __shfl_up(incl, off);
    if (lane >= off) incl += n;
  }
  float r2 = incl - run;
  for (int i = 0; i < 32; ++i) {
    r2 += A_in[(base + i) * NH + h];
    Ac[h * L_SEQ + base + i] = r2;
  }
}

// ---------------- causal depthwise conv K=2 (+ v *= dt), fp16 out ----------
// All QKV channels -> qc [L][3072] fp16 (row-major, fully coalesced).
__global__ __launch_bounds__(256) void conv_kernel(
    const float* __restrict__ qkv, const float* __restrict__ smallf,
    const float* __restrict__ dt, unsigned short* __restrict__ qc)
{
  const int idx = blockIdx.x * 256 + threadIdx.x;
  const int l = idx / (QKV_N / 4);
  const int c = (idx % (QKV_N / 4)) * 4;
  f4 xc = *(const f4*)&qkv[(size_t)l * QKV_N + c];
  f4 xp = (f4){0.f, 0.f, 0.f, 0.f};
  if (l > 0) xp = *(const f4*)&qkv[(size_t)(l - 1) * QKV_N + c];
  const float* w; const float* b; int cb;
  if (c < HIDN)          { w = smallf;        b = smallf + 2048; cb = c; }
  else if (c < 2 * HIDN) { w = smallf + 3072; b = smallf + 5120; cb = c - HIDN; }
  else                   { w = smallf + 6144; b = smallf + 8192; cb = c - 2 * HIDN; }
  f4 o;
#pragma unroll
  for (int j = 0; j < 4; ++j)
    o[j] = b[cb + j] + xp[j] * w[(cb + j) * 2] + xc[j] * w[(cb + j) * 2 + 1];
  if (c >= 2 * HIDN) {
    const int hh = (c - 2 * HIDN) >> 6;
    o *= dt[l * NH + hh];
  }
  ushort4 st;
  st.x = f2h(o[0]); st.y = f2h(o[1]); st.z = f2h(o[2]); st.w = f2h(o[3]);
  *(ushort4*)&qc[(size_t)l * QKV_N + c] = st;
}

// ---------------- V transpose: qc V-part -> vt [NH][DHD][L] (LDS-tiled) ----
__global__ __launch_bounds__(256) void transpose_v(
    const unsigned short* __restrict__ qc, unsigned short* __restrict__ vt)
{
  const int h = blockIdx.y;
  const int l0 = blockIdx.x * 64;
  const int t = threadIdx.x;
  const int srow = t >> 2, cc = t & 3;
  __shared__ __align__(16) unsigned short Ts[64 * 68];
  const unsigned short* gp =
      qc + (size_t)(l0 + srow) * QKV_N + 2 * HIDN + h * DHD + cc * 16;
  uint4 a = *(const uint4*)gp;
  uint4 b = *(const uint4*)(gp + 8);
  *(uint4*)&Ts[srow * 68 + cc * 16] = a;
  *(uint4*)&Ts[srow * 68 + cc * 16 + 8] = b;
  __syncthreads();
  __align__(16) unsigned short o[16];
#pragma unroll
  for (int j = 0; j < 16; ++j) o[j] = Ts[(cc * 16 + j) * 68 + srow];
  unsigned short* op = vt + ((size_t)h * DHD + srow) * L_SEQ + l0 + cc * 16;
  *(uint4*)op = *(const uint4*)&o[0];
  *(uint4*)(op + 8) = *(const uint4*)&o[8];
}

// ---------------- gated causal attention + RMSNorm (MFMA fp16) -------------
// grid (32, NH), 256 threads = 4 waves, one 64-row l-tile per block.
// lt = (h<8) ? 31-bx : bx  => co-resident blocks (n, n+256) share bx but get
// complementary weights (32-bx)+(bx+1)=33 -> every CU does the average work.
// K/V double-buffered in LDS -> ONE barrier per kv-iteration.
// S roundtrip is wave-private -> no barrier between gate and PV.
__global__ __launch_bounds__(256) void attn_kernel(
    const unsigned short* __restrict__ qc,     // fp16 [L][3072] (Q,K,V)
    const unsigned short* __restrict__ vt,     // fp16 [NH][DHD][L] (V^T)
    const float* __restrict__ Ac,              // [NH][L]
    const float* __restrict__ smallf,
    unsigned short* __restrict__ attn_out)     // bf16 [L][1024]
{
  const int h  = blockIdx.y;
  const int bx = blockIdx.x;
  const int lt = (h < 8) ? (31 - bx) : bx;
  const int t  = threadIdx.x;              // 0..255
  const int w    = t >> 6;                 // wave 0..3
  const int lane = t & 63;
  const int l16  = lane & 15;
  const int quad = lane >> 4;
  const int srow = t >> 2;                 // staging row 0..63
  const int cc   = t & 3;                  // staging col chunk

  __shared__ __align__(16) unsigned short K_lds[2][64 * 68];  // K[m][d]
  __shared__ __align__(16) unsigned short V_lds[2][64 * 68];  // V^T[d][m]
  __shared__ __align__(16) unsigned short S_lds[64 * 68];     // S[l][m]

  const int l0 = lt * 64;
  const float rc = 1.0f / smallf[9328 + h];
  const float* Acp = Ac + h * L_SEQ;

  // Q A-fragments held in registers: row = l16, k(d) = ks*32 + quad*8 + j
  H8 qf0, qf1;
  {
    const unsigned short* qp =
        qc + (size_t)(l0 + w * 16 + l16) * QKV_N + h * DHD + quad * 8;
    qf0.u4 = *(const uint4*)qp;
    qf1.u4 = *(const uint4*)(qp + 32);
  }
  float alv[4];
#pragma unroll
  for (int r = 0; r < 4; ++r) alv[r] = Acp[l0 + w * 16 + quad * 4 + r];

  f4 acc[4];
#pragma unroll
  for (int i = 0; i < 4; ++i) acc[i] = (f4){0.f, 0.f, 0.f, 0.f};

  const unsigned short* kgp =
      qc + (size_t)srow * QKV_N + HIDN + h * DHD + cc * 16;
  const unsigned short* vgp =
      vt + ((size_t)h * DHD + srow) * L_SEQ + cc * 16;

  const int swo = srow * 68 + cc * 16;

  // prologue: tile 0 in registers
  uint4 k0v = *(const uint4*)kgp,       k1v = *(const uint4*)(kgp + 8);
  uint4 v0v = *(const uint4*)vgp,       v1v = *(const uint4*)(vgp + 8);

  int cur = 0;
  for (int it = 0; it <= lt; ++it) {
    unsigned short* Kl = K_lds[cur];
    unsigned short* Vl = V_lds[cur];
    // stage current tile (WAR-safe: barrier drains all LDS ops each iter)
    *(u32x2*)&Kl[swo]      = (u32x2){k0v.x, k0v.y};
    *(u32x2*)&Kl[swo + 4]  = (u32x2){k0v.z, k0v.w};
    *(u32x2*)&Kl[swo + 8]  = (u32x2){k1v.x, k1v.y};
    *(u32x2*)&Kl[swo + 12] = (u32x2){k1v.z, k1v.w};
    *(u32x2*)&Vl[swo]      = (u32x2){v0v.x, v0v.y};
    *(u32x2*)&Vl[swo + 4]  = (u32x2){v0v.z, v0v.w};
    *(u32x2*)&Vl[swo + 8]  = (u32x2){v1v.x, v1v.y};
    *(u32x2*)&Vl[swo + 12] = (u32x2){v1v.z, v1v.w};
    if (it < lt) {                                // prefetch next tile
      const unsigned short* kp = kgp + (size_t)(it + 1) * 64 * QKV_N;
      const unsigned short* vp = vgp + (size_t)(it + 1) * 64;
      k0v = *(const uint4*)kp; k1v = *(const uint4*)(kp + 8);
      v0v = *(const uint4*)vp; v1v = *(const uint4*)(vp + 8);
    }
    __syncthreads();                              // staging visible

    // ---- QK^T: S[l][m] ----
    f4 s[4];
#pragma unroll
    for (int i = 0; i < 4; ++i) s[i] = (f4){0.f, 0.f, 0.f, 0.f};
#pragma unroll
    for (int ks = 0; ks < 2; ++ks) {
      H8 qk = ks ? qf1 : qf0;
#pragma unroll
      for (int nt = 0; nt < 4; ++nt) {
        H8 kf;
        const int ko = (nt * 16 + l16) * 68 + ks * 32 + quad * 8;
        kf.u2[0] = *(const u32x2*)&K_lds[cur][ko];
        kf.u2[1] = *(const u32x2*)&K_lds[cur][ko + 4];
        s[nt] = __builtin_amdgcn_mfma_f32_16x16x32_f16(qk.h, kf.h, s[nt], 0, 0, 0);
      }
    }
    // ---- gate: s * exp(Ac_l - Ac_m) * rc, causal mask; write S fp16 ----
    const int m0 = it * 64;
#pragma unroll
    for (int nt = 0; nt < 4; ++nt) {
      const int mg = m0 + nt * 16 + l16;
      const float am = Acp[mg];
#pragma unroll
      for (int r = 0; r < 4; ++r) {
        const int lg = l0 + w * 16 + quad * 4 + r;
        float val = (mg <= lg) ? s[nt][r] * __expf(alv[r] - am) * rc : 0.0f;
        S_lds[(w * 16 + quad * 4 + r) * 68 + nt * 16 + l16] = f2h(val);
      }
    }
    // ---- PV: O[l][d] += S[l][m] * V[m][d] (wave-private S rows) ----
#pragma unroll
    for (int ks = 0; ks < 2; ++ks) {
      H8 sa;
      const int so = (w * 16 + l16) * 68 + ks * 32 + quad * 8;
      sa.u2[0] = *(const u32x2*)&S_lds[so];
      sa.u2[1] = *(const u32x2*)&S_lds[so + 4];
#pragma unroll
      for (int db = 0; db < 4; ++db) {
        H8 vb;
        const int vo = (db * 16 + l16) * 68 + ks * 32 + quad * 8;
        vb.u2[0] = *(const u32x2*)&V_lds[cur][vo];
        vb.u2[1] = *(const u32x2*)&V_lds[cur][vo + 4];
        acc[db] = __builtin_amdgcn_mfma_f32_16x16x32_f16(sa.h, vb.h, acc[db], 0, 0, 0);
      }
    }
    cur ^= 1;
  }

  // ---- RMSNorm over d=64 and bf16 store ----
#pragma unroll
  for (int r = 0; r < 4; ++r) {
    float p = acc[0][r] * acc[0][r] + acc[1][r] * acc[1][r]
            + acc[2][r] * acc[2][r] + acc[3][r] * acc[3][r];
#pragma unroll
    for (int off = 1; off < 16; off <<= 1) p += __shfl_xor(p, off);
    const float rn = rsqrtf(p * (1.0f / 64.0f) + 1.1920928955078125e-07f);
    unsigned short* op =
        attn_out + (size_t)(l0 + w * 16 + quad * 4 + r) * HIDN + h * DHD + l16;
#pragma unroll
    for (int ds = 0; ds < 4; ++ds)
      op[ds * 16] = f2b(acc[ds][r] * rn * smallf[9216 + ds * 16 + l16]);
  }
}

extern "C" void kernel_launch(void* const* d_in, const int* in_sizes, int n_in,
                              void* d_out, int out_size, void* d_ws, size_t ws_size,
                              hipStream_t stream)
{
  (void)in_sizes; (void)n_in; (void)out_size; (void)ws_size;
  const void* hs        = d_in[0];
  // d_in[1] = attention_mask: deterministic causal triu — handled analytically
  const void* qkv_w     = d_in[2];
  const void* q_conv_w  = d_in[3];
  const void* q_conv_b  = d_in[4];
  const void* k_conv_w  = d_in[5];
  const void* k_conv_b  = d_in[6];
  const void* v_conv_w  = d_in[7];
  const void* v_conv_b  = d_in[8];
  const void* norm_w    = d_in[9];
  const void* A_log     = d_in[10];
  const void* dt_bias   = d_in[11];
  const void* dt_proj_w = d_in[12];
  const void* dt_proj_b = d_in[13];
  const void* o_w       = d_in[14];
  const void* ordc      = d_in[15];

  char* ws = (char*)d_ws;
  int* flag             = (int*)ws;                              // @0
  unsigned short* hs_b  = (unsigned short*)(ws + 256);           // 2097152*2
  unsigned short* qkvw_b= (unsigned short*)(ws + 4194560);       // 3145728*2
  unsigned short* ow_b  = (unsigned short*)(ws + 10486016);      // 1048576*2
  unsigned short* dtw_b = (unsigned short*)(ws + 12583168);      // 16384*2
  float* smallf         = (float*)(ws + 12615936);               // 9344*4
  float* qkv            = (float*)(ws + 12653568);               // 25165824 (fp32)
  unsigned short* qc_h  = (unsigned short*)(ws + 37819392);      // fp16 12.6MB
  float* dtbuf          = (float*)(ws + 62985216);               // 131072
  float* Abuf           = (float*)(ws + 63116288);               // 131072
  float* Acum           = (float*)(ws + 63247360);               // 131072
  unsigned short* attnb = (unsigned short*)(ws + 63378432);      // 2097152*2
  unsigned short* vt_h  = (unsigned short*)(ws + 67572736);      // 2097152*2 (V^T fp16)

  detect_kernel<<<1, 256, 0, stream>>>((const unsigned short*)hs, flag);
  convert_big<<<(2097152 / 4 + 255) / 256, 256, 0, stream>>>(hs, hs_b, 2097152, flag);
  convert_big<<<(3145728 / 4 + 255) / 256, 256, 0, stream>>>(qkv_w, qkvw_b, 3145728, flag);
  convert_big<<<(1048576 / 4 + 255) / 256, 256, 0, stream>>>(o_w, ow_b, 1048576, flag);
  convert_big<<<(16384 / 4 + 255) / 256, 256, 0, stream>>>(dt_proj_w, dtw_b, 16384, flag);
  convert_small<<<4, 256, 0, stream>>>(q_conv_w, q_conv_b, k_conv_w, k_conv_b,
                                       v_conv_w, v_conv_b, norm_w, A_log,
                                       dt_bias, dt_proj_b, ordc, smallf, flag);

  gemm128<<<dim3(QKV_N / 128, L_SEQ / 128), 256, 0, stream>>>(
      hs_b, qkvw_b, qkv, L_SEQ, QKV_N, HIDN);
  dt_kernel<<<L_SEQ, 256, 0, stream>>>(hs_b, dtw_b, smallf, dtbuf, Abuf);
  cumsum_kernel<<<NH, 64, 0, stream>>>(Abuf, Acum);
  conv_kernel<<<(L_SEQ * QKV_N / 4) / 256, 256, 0, stream>>>(qkv, smallf, dtbuf, qc_h);
  transpose_v<<<dim3(L_SEQ / 64, NH), 256, 0, stream>>>(qc_h, vt_h);
  attn_kernel<<<dim3(32, NH), 256, 0, stream>>>(qc_h, vt_h, Acum, smallf, attnb);
  gemm_bt<1><<<dim3(HIDN / 64, L_SEQ / 64), 256, 0, stream>>>(
      attnb, ow_b, d_out, L_SEQ, HIDN, HIDN, flag);
}

// Round 7
// 244.018 us; speedup vs baseline: 4.9174x; 1.0536x over previous
//
#include <hip/hip_runtime.h>
#include <hip/hip_bf16.h>

#define L_SEQ 2048
#define HIDN  1024
#define NH    16
#define DHD   64
#define QKV_N 3072

typedef float f4 __attribute__((ext_vector_type(4)));
typedef __bf16 bf16x8 __attribute__((ext_vector_type(8)));
typedef _Float16 half8 __attribute__((ext_vector_type(8)));
typedef unsigned int u32x2 __attribute__((ext_vector_type(2)));

union H8 {
  half8 h;
  u32x2 u2[2];
  uint4 u4;
};

__device__ __forceinline__ float b2f(unsigned short u) {
  union { unsigned int i; float f; } c; c.i = ((unsigned int)u) << 16; return c.f;
}
__device__ __forceinline__ unsigned short f2b(float f) {
  union { float f; unsigned int i; } c; c.f = f;
  unsigned int r = c.i + 0x7FFFu + ((c.i >> 16) & 1u);
  return (unsigned short)(r >> 16);
}
__device__ __forceinline__ unsigned short f2h(float f) {
  union { _Float16 h; unsigned short u; } c; c.h = (_Float16)f; return c.u;
}
__device__ __forceinline__ void unpack8(uint4 u, float* f) {
  unsigned int w[4] = {u.x, u.y, u.z, u.w};
#pragma unroll
  for (int i = 0; i < 4; ++i) {
    union { unsigned int i_; float f_; } lo, hi;
    lo.i_ = w[i] << 16;
    hi.i_ = w[i] & 0xffff0000u;
    f[2 * i] = lo.f_; f[2 * i + 1] = hi.f_;
  }
}

// ------------- fused prep: dtype detect + canonicalize all params ----------
// Each block redundantly detects the input dtype (deterministic) -> no grid
// sync needed. Replaces 6 kernel launches with 1.
// smallf layout: qw@0(2048) qb@2048(1024) kw@3072(2048) kb@5120(1024)
// vw@6144(2048) vb@8192(1024) nw@9216(64) al@9280(16) dt_bias@9296(16)
// dt_proj_b@9312(16) oc@9328(16)  total 9344
__global__ __launch_bounds__(256) void prep_kernel(
    const void* hs, const void* qkvw, const void* ow, const void* dtw,
    const void* qw, const void* qb, const void* kw, const void* kb,
    const void* vw, const void* vb, const void* nw, const void* al,
    const void* dtb, const void* dpb, const void* oc,
    unsigned short* __restrict__ hs_b, unsigned short* __restrict__ qkvw_b,
    unsigned short* __restrict__ ow_b, unsigned short* __restrict__ dtw_b,
    float* __restrict__ smallf, int* __restrict__ flag)
{
  __shared__ int cnt;
  if (threadIdx.x == 0) cnt = 0;
  __syncthreads();
  {
    const unsigned short* p = (const unsigned short*)hs;
    int c = 0;
    for (int i = threadIdx.x; i < 8192; i += 256)
      if (((p[i] >> 7) & 0xFFu) >= 140u) c++;
    atomicAdd(&cnt, c);
  }
  __syncthreads();
  const int f = (cnt >= 32) ? 1 : 0;          // 1 = fp32 inputs
  if (blockIdx.x == 0 && threadIdx.x == 0) *flag = f;

  const int tid = blockIdx.x * 256 + threadIdx.x;
  const int nth = gridDim.x * 256;
  // big arrays, 4-elem granularity: hs 524288 | qkvw 786432 | ow 262144 | dtw 4096
  for (int i = tid; i < 1576960; i += nth) {
    const void* src; unsigned short* dst; int off;
    if (i < 524288)       { src = hs;   dst = hs_b;   off = i; }
    else if (i < 1310720) { src = qkvw; dst = qkvw_b; off = i - 524288; }
    else if (i < 1572864) { src = ow;   dst = ow_b;   off = i - 1310720; }
    else                  { src = dtw;  dst = dtw_b;  off = i - 1572864; }
    const int e = off * 4;
    if (f) {
      f4 v = *(const f4*)((const float*)src + e);
      ushort4 o;
      o.x = f2b(v[0]); o.y = f2b(v[1]); o.z = f2b(v[2]); o.w = f2b(v[3]);
      *(ushort4*)(dst + e) = o;
    } else {
      *(uint2*)(dst + e) = *(const uint2*)((const unsigned short*)src + e);
    }
  }
  const void* ptrs[11] = {qw, qb, kw, kb, vw, vb, nw, al, dtb, dpb, oc};
  const int sizes[11] = {2048, 1024, 2048, 1024, 2048, 1024, 64, 16, 16, 16, 16};
  int off = 0;
  for (int a = 0; a < 11; ++a) {
    for (int i = tid; i < sizes[a]; i += nth)
      smallf[off + i] = f ? ((const float*)ptrs[a])[i]
                          : b2f(((const unsigned short*)ptrs[a])[i]);
    off += sizes[a];
  }
}

// ------- C = A (MxK) * B^T (NxK), bf16 in, fp32 out, 128x128 tile ---------
// 256 threads = 4 waves (2x2), each wave owns a 64x64 sub-tile (4x4 frags).
__global__ __launch_bounds__(256) void gemm128(
    const unsigned short* __restrict__ A, const unsigned short* __restrict__ B,
    float* __restrict__ C, int M, int N, int K)
{
  __shared__ __align__(16) unsigned short As[128 * 40];
  __shared__ __align__(16) unsigned short Bs[128 * 40];
  const int t = threadIdx.x;
  const int w = t >> 6, lane = t & 63;
  const int quad = lane >> 4, l16 = lane & 15;
  const int wr = w >> 1, wc = w & 1;
  const int m0 = blockIdx.y * 128, n0 = blockIdx.x * 128;
  const int srow = t >> 1;             // 0..127
  const int scol = (t & 1) * 16;       // elements (16B chunk pair)

  f4 acc[4][4];
#pragma unroll
  for (int i = 0; i < 4; ++i)
#pragma unroll
    for (int j = 0; j < 4; ++j) acc[i][j] = (f4){0.f, 0.f, 0.f, 0.f};

  const unsigned short* apg = A + (size_t)(m0 + srow) * K + scol;
  const unsigned short* bpg = B + (size_t)(n0 + srow) * K + scol;
  uint4 a0 = *(const uint4*)apg,       a1 = *(const uint4*)(apg + 8);
  uint4 b0 = *(const uint4*)bpg,       b1 = *(const uint4*)(bpg + 8);

  for (int k0 = 0; k0 < K; k0 += 32) {
    __syncthreads();                       // WAR: prev compute done
    *(uint4*)&As[srow * 40 + scol]     = a0;
    *(uint4*)&As[srow * 40 + scol + 8] = a1;
    *(uint4*)&Bs[srow * 40 + scol]     = b0;
    *(uint4*)&Bs[srow * 40 + scol + 8] = b1;
    __syncthreads();                       // staging visible
    if (k0 + 32 < K) {                     // prefetch next K-tile (overlaps MFMA)
      a0 = *(const uint4*)(apg + k0 + 32); a1 = *(const uint4*)(apg + k0 + 40);
      b0 = *(const uint4*)(bpg + k0 + 32); b1 = *(const uint4*)(bpg + k0 + 40);
    }
    bf16x8 aF[4], bF[4];
#pragma unroll
    for (int i = 0; i < 4; ++i)
      aF[i] = *(const bf16x8*)&As[(wr * 64 + i * 16 + l16) * 40 + quad * 8];
#pragma unroll
    for (int j = 0; j < 4; ++j)
      bF[j] = *(const bf16x8*)&Bs[(wc * 64 + j * 16 + l16) * 40 + quad * 8];
#pragma unroll
    for (int i = 0; i < 4; ++i)
#pragma unroll
      for (int j = 0; j < 4; ++j)
        acc[i][j] = __builtin_amdgcn_mfma_f32_16x16x32_bf16(aF[i], bF[j], acc[i][j], 0, 0, 0);
  }

#pragma unroll
  for (int i = 0; i < 4; ++i)
#pragma unroll
    for (int j = 0; j < 4; ++j)
#pragma unroll
      for (int r = 0; r < 4; ++r) {
        int m = m0 + wr * 64 + i * 16 + quad * 4 + r;
        int n = n0 + wc * 64 + j * 16 + l16;
        C[(size_t)m * N + n] = acc[i][j][r];
      }
}

// ---------------- C = A (MxK) * B^T (NxK), bf16 in, fp32 acc ----------------
template <int MODE>
__global__ __launch_bounds__(256) void gemm_bt(
    const unsigned short* __restrict__ A, const unsigned short* __restrict__ B,
    void* __restrict__ Cv, int M, int N, int K, const int* __restrict__ flag)
{
  __shared__ __align__(16) short As[64 * 40];
  __shared__ __align__(16) short Bs[64 * 40];
  const int t = threadIdx.x;
  const int wave = t >> 6, lane = t & 63;
  const int quad = lane >> 4, l16 = lane & 15;
  const int m0 = blockIdx.y * 64, n0 = blockIdx.x * 64;
  const int srow = t >> 2, scol = (t & 3) * 8;
  f4 acc[4];
#pragma unroll
  for (int i = 0; i < 4; ++i) acc[i] = (f4){0.f, 0.f, 0.f, 0.f};
  const unsigned short* ap = A + (size_t)(m0 + srow) * K + scol;
  const unsigned short* bp = B + (size_t)(n0 + srow) * K + scol;
  for (int k0 = 0; k0 < K; k0 += 32) {
    uint4 av = *(const uint4*)(ap + k0);
    uint4 bv = *(const uint4*)(bp + k0);
    __syncthreads();
    *(uint4*)&As[srow * 40 + scol] = av;
    *(uint4*)&Bs[srow * 40 + scol] = bv;
    __syncthreads();
    bf16x8 af = *(const bf16x8*)&As[(wave * 16 + l16) * 40 + quad * 8];
#pragma unroll
    for (int nt = 0; nt < 4; ++nt) {
      bf16x8 bf = *(const bf16x8*)&Bs[(nt * 16 + l16) * 40 + quad * 8];
      acc[nt] = __builtin_amdgcn_mfma_f32_16x16x32_bf16(af, bf, acc[nt], 0, 0, 0);
    }
  }
  const int outf32 = (MODE == 0) ? 1 : (*flag ? 1 : 0);
#pragma unroll
  for (int nt = 0; nt < 4; ++nt) {
#pragma unroll
    for (int r = 0; r < 4; ++r) {
      int m = m0 + wave * 16 + quad * 4 + r;
      int n = n0 + nt * 16 + l16;
      if (outf32) ((float*)Cv)[(size_t)m * N + n] = acc[nt][r];
      else        ((unsigned short*)Cv)[(size_t)m * N + n] = f2b(acc[nt][r]);
    }
  }
}

// ---------------- dt = softplus(hs @ dtw^T + dt_proj_b + dt_bias) ----------
__global__ __launch_bounds__(256) void dt_kernel(
    const unsigned short* __restrict__ hs,
    const unsigned short* __restrict__ dtw,
    const float* __restrict__ smallf,
    float* __restrict__ dt_out, float* __restrict__ A_out)
{
  const int l = blockIdx.x;
  const int t = threadIdx.x, wave = t >> 6, lane = t & 63;
  const unsigned short* hp = hs + (size_t)l * HIDN + lane * 16;
  float hv[16];
  unpack8(*(const uint4*)hp, hv);
  unpack8(*(const uint4*)(hp + 8), hv + 8);
#pragma unroll
  for (int hh = 0; hh < 4; ++hh) {
    const int hd = wave * 4 + hh;
    const unsigned short* wp = dtw + (size_t)hd * HIDN + lane * 16;
    float wv[16];
    unpack8(*(const uint4*)wp, wv);
    unpack8(*(const uint4*)(wp + 8), wv + 8);
    float p = 0.f;
#pragma unroll
    for (int i = 0; i < 16; ++i) p += hv[i] * wv[i];
#pragma unroll
    for (int off = 32; off > 0; off >>= 1) p += __shfl_down(p, off);
    if (lane == 0) {
      float z = p + smallf[9312 + hd] + smallf[9296 + hd];
      float dtv = (z > 20.f) ? z : log1pf(expf(z));
      dt_out[l * NH + hd] = dtv;
      A_out[l * NH + hd] = -expf(smallf[9280 + hd]) * dtv;
    }
  }
}

// ---------------- per-head inclusive cumsum over L ----------------
__global__ __launch_bounds__(64) void cumsum_kernel(const float* __restrict__ A_in,
                                                    float* __restrict__ Ac)
{
  const int h = blockIdx.x;
  const int lane = threadIdx.x;
  const int base = lane * 32;
  float run = 0.f;
  for (int i = 0; i < 32; ++i) run += A_in[(base + i) * NH + h];
  float incl = run;
#pragma unroll
  for (int off = 1; off < 64; off <<= 1) {
    float n = __shfl_up(incl, off);
    if (lane >= off) incl += n;
  }
  float r2 = incl - run;
  for (int i = 0; i < 32; ++i) {
    r2 += A_in[(base + i) * NH + h];
    Ac[h * L_SEQ + base + i] = r2;
  }
}

// ---------------- causal depthwise conv K=2 (+ v *= dt), fp16 out ----------
__global__ __launch_bounds__(256) void conv_kernel(
    const float* __restrict__ qkv, const float* __restrict__ smallf,
    const float* __restrict__ dt, unsigned short* __restrict__ qc)
{
  const int idx = blockIdx.x * 256 + threadIdx.x;
  const int l = idx / (QKV_N / 4);
  const int c = (idx % (QKV_N / 4)) * 4;
  f4 xc = *(const f4*)&qkv[(size_t)l * QKV_N + c];
  f4 xp = (f4){0.f, 0.f, 0.f, 0.f};
  if (l > 0) xp = *(const f4*)&qkv[(size_t)(l - 1) * QKV_N + c];
  const float* w; const float* b; int cb;
  if (c < HIDN)          { w = smallf;        b = smallf + 2048; cb = c; }
  else if (c < 2 * HIDN) { w = smallf + 3072; b = smallf + 5120; cb = c - HIDN; }
  else                   { w = smallf + 6144; b = smallf + 8192; cb = c - 2 * HIDN; }
  f4 o;
#pragma unroll
  for (int j = 0; j < 4; ++j)
    o[j] = b[cb + j] + xp[j] * w[(cb + j) * 2] + xc[j] * w[(cb + j) * 2 + 1];
  if (c >= 2 * HIDN) {
    const int hh = (c - 2 * HIDN) >> 6;
    o *= dt[l * NH + hh];
  }
  ushort4 st;
  st.x = f2h(o[0]); st.y = f2h(o[1]); st.z = f2h(o[2]); st.w = f2h(o[3]);
  *(ushort4*)&qc[(size_t)l * QKV_N + c] = st;
}

// ---------------- V transpose: qc V-part -> vt [NH][DHD][L] (LDS-tiled) ----
__global__ __launch_bounds__(256) void transpose_v(
    const unsigned short* __restrict__ qc, unsigned short* __restrict__ vt)
{
  const int h = blockIdx.y;
  const int l0 = blockIdx.x * 64;
  const int t = threadIdx.x;
  const int srow = t >> 2, cc = t & 3;
  __shared__ __align__(16) unsigned short Ts[64 * 68];
  const unsigned short* gp =
      qc + (size_t)(l0 + srow) * QKV_N + 2 * HIDN + h * DHD + cc * 16;
  uint4 a = *(const uint4*)gp;
  uint4 b = *(const uint4*)(gp + 8);
  *(uint4*)&Ts[srow * 68 + cc * 16] = a;
  *(uint4*)&Ts[srow * 68 + cc * 16 + 8] = b;
  __syncthreads();
  __align__(16) unsigned short o[16];
#pragma unroll
  for (int j = 0; j < 16; ++j) o[j] = Ts[(cc * 16 + j) * 68 + srow];
  unsigned short* op = vt + ((size_t)h * DHD + srow) * L_SEQ + l0 + cc * 16;
  *(uint4*)op = *(const uint4*)&o[0];
  *(uint4*)(op + 8) = *(const uint4*)&o[8];
}

// ---------------- gated causal attention + RMSNorm (MFMA fp16) -------------
// grid (32, NH), 256 threads = 4 waves, one 64-row l-tile per block.
// Tile map: base=(bx&1)? bx/2 : 31-bx/2; lt=(h<8)? base : 31-base.
//   -> consecutive pairs (2k,2k+1) sum to 33 iters AND (n,n+256) pairs sum
//      to 33 iters: balanced under round-robin, consecutive, and XCD-major
//      block->CU mappings.
// Loop order [prefetch][compute][stage][barrier]: global loads are consumed
// by the stage at the END of compute, so the barrier's implicit vmcnt(0)
// drain costs nothing (T14 issue-early/write-late).
__global__ __launch_bounds__(256) void attn_kernel(
    const unsigned short* __restrict__ qc,     // fp16 [L][3072] (Q,K,V)
    const unsigned short* __restrict__ vt,     // fp16 [NH][DHD][L] (V^T)
    const float* __restrict__ Ac,              // [NH][L]
    const float* __restrict__ smallf,
    unsigned short* __restrict__ attn_out)     // bf16 [L][1024]
{
  const int h  = blockIdx.y;
  const int bx = blockIdx.x;
  const int jj = bx >> 1;
  const int base = (bx & 1) ? jj : (31 - jj);
  const int lt = (h < 8) ? base : (31 - base);
  const int t  = threadIdx.x;              // 0..255
  const int w    = t >> 6;                 // wave 0..3
  const int lane = t & 63;
  const int l16  = lane & 15;
  const int quad = lane >> 4;
  const int srow = t >> 2;                 // staging row 0..63
  const int cc   = t & 3;                  // staging col chunk

  __shared__ __align__(16) unsigned short K_lds[2][64 * 68];  // K[m][d]
  __shared__ __align__(16) unsigned short V_lds[2][64 * 68];  // V^T[d][m]
  __shared__ __align__(16) unsigned short S_lds[64 * 68];     // S[l][m]

  const int l0 = lt * 64;
  const float rc = 1.0f / smallf[9328 + h];
  const float* Acp = Ac + h * L_SEQ;

  // Q A-fragments held in registers: row = l16, k(d) = ks*32 + quad*8 + j
  H8 qf0, qf1;
  {
    const unsigned short* qp =
        qc + (size_t)(l0 + w * 16 + l16) * QKV_N + h * DHD + quad * 8;
    qf0.u4 = *(const uint4*)qp;
    qf1.u4 = *(const uint4*)(qp + 32);
  }
  float alv[4];
#pragma unroll
  for (int r = 0; r < 4; ++r) alv[r] = Acp[l0 + w * 16 + quad * 4 + r];

  f4 acc[4];
#pragma unroll
  for (int i = 0; i < 4; ++i) acc[i] = (f4){0.f, 0.f, 0.f, 0.f};

  const unsigned short* kgp =
      qc + (size_t)srow * QKV_N + HIDN + h * DHD + cc * 16;
  const unsigned short* vgp =
      vt + ((size_t)h * DHD + srow) * L_SEQ + cc * 16;

  const int swo = srow * 68 + cc * 16;

  // prologue: tile 0 regs + its gate coefficients, stage, barrier
  uint4 k0v = *(const uint4*)kgp,       k1v = *(const uint4*)(kgp + 8);
  uint4 v0v = *(const uint4*)vgp,       v1v = *(const uint4*)(vgp + 8);
  float amv[4];
#pragma unroll
  for (int nt = 0; nt < 4; ++nt) amv[nt] = Acp[nt * 16 + l16];

  *(u32x2*)&K_lds[0][swo]      = (u32x2){k0v.x, k0v.y};
  *(u32x2*)&K_lds[0][swo + 4]  = (u32x2){k0v.z, k0v.w};
  *(u32x2*)&K_lds[0][swo + 8]  = (u32x2){k1v.x, k1v.y};
  *(u32x2*)&K_lds[0][swo + 12] = (u32x2){k1v.z, k1v.w};
  *(u32x2*)&V_lds[0][swo]      = (u32x2){v0v.x, v0v.y};
  *(u32x2*)&V_lds[0][swo + 4]  = (u32x2){v0v.z, v0v.w};
  *(u32x2*)&V_lds[0][swo + 8]  = (u32x2){v1v.x, v1v.y};
  *(u32x2*)&V_lds[0][swo + 12] = (u32x2){v1v.z, v1v.w};
  __syncthreads();

  int cur = 0;
  for (int it = 0; it <= lt; ++it) {
    // ---- issue next-tile prefetch (covered by this iteration's compute) ----
    uint4 nk0 = k0v, nk1 = k1v, nv0 = v0v, nv1 = v1v;
    float namv[4];
    const bool more = (it < lt);
    if (more) {
      const unsigned short* kp = kgp + (size_t)(it + 1) * 64 * QKV_N;
      const unsigned short* vp = vgp + (size_t)(it + 1) * 64;
      nk0 = *(const uint4*)kp; nk1 = *(const uint4*)(kp + 8);
      nv0 = *(const uint4*)vp; nv1 = *(const uint4*)(vp + 8);
#pragma unroll
      for (int nt = 0; nt < 4; ++nt)
        namv[nt] = Acp[(it + 1) * 64 + nt * 16 + l16];
    }

    // ---- QK^T: S[l][m] ----
    f4 s[4];
#pragma unroll
    for (int i = 0; i < 4; ++i) s[i] = (f4){0.f, 0.f, 0.f, 0.f};
#pragma unroll
    for (int ks = 0; ks < 2; ++ks) {
      H8 qk = ks ? qf1 : qf0;
#pragma unroll
      for (int nt = 0; nt < 4; ++nt) {
        H8 kf;
        const int ko = (nt * 16 + l16) * 68 + ks * 32 + quad * 8;
        kf.u2[0] = *(const u32x2*)&K_lds[cur][ko];
        kf.u2[1] = *(const u32x2*)&K_lds[cur][ko + 4];
        s[nt] = __builtin_amdgcn_mfma_f32_16x16x32_f16(qk.h, kf.h, s[nt], 0, 0, 0);
      }
    }
    // ---- gate: s * exp(Ac_l - Ac_m) * rc, causal mask; write S fp16 ----
    const int m0 = it * 64;
#pragma unroll
    for (int nt = 0; nt < 4; ++nt) {
      const int mg = m0 + nt * 16 + l16;
      const float am = amv[nt];
#pragma unroll
      for (int r = 0; r < 4; ++r) {
        const int lg = l0 + w * 16 + quad * 4 + r;
        float val = (mg <= lg) ? s[nt][r] * __expf(alv[r] - am) * rc : 0.0f;
        S_lds[(w * 16 + quad * 4 + r) * 68 + nt * 16 + l16] = f2h(val);
      }
    }
    // ---- PV: O[l][d] += S[l][m] * V[m][d] (wave-private S rows) ----
#pragma unroll
    for (int ks = 0; ks < 2; ++ks) {
      H8 sa;
      const int so = (w * 16 + l16) * 68 + ks * 32 + quad * 8;
      sa.u2[0] = *(const u32x2*)&S_lds[so];
      sa.u2[1] = *(const u32x2*)&S_lds[so + 4];
#pragma unroll
      for (int db = 0; db < 4; ++db) {
        H8 vb;
        const int vo = (db * 16 + l16) * 68 + ks * 32 + quad * 8;
        vb.u2[0] = *(const u32x2*)&V_lds[cur][vo];
        vb.u2[1] = *(const u32x2*)&V_lds[cur][vo + 4];
        acc[db] = __builtin_amdgcn_mfma_f32_16x16x32_f16(sa.h, vb.h, acc[db], 0, 0, 0);
      }
    }
    // ---- stage next tile into the other buffer, then one barrier ----
    if (more) {
      unsigned short* Kl = K_lds[cur ^ 1];
      unsigned short* Vl = V_lds[cur ^ 1];
      *(u32x2*)&Kl[swo]      = (u32x2){nk0.x, nk0.y};
      *(u32x2*)&Kl[swo + 4]  = (u32x2){nk0.z, nk0.w};
      *(u32x2*)&Kl[swo + 8]  = (u32x2){nk1.x, nk1.y};
      *(u32x2*)&Kl[swo + 12] = (u32x2){nk1.z, nk1.w};
      *(u32x2*)&Vl[swo]      = (u32x2){nv0.x, nv0.y};
      *(u32x2*)&Vl[swo + 4]  = (u32x2){nv0.z, nv0.w};
      *(u32x2*)&Vl[swo + 8]  = (u32x2){nv1.x, nv1.y};
      *(u32x2*)&Vl[swo + 12] = (u32x2){nv1.z, nv1.w};
#pragma unroll
      for (int nt = 0; nt < 4; ++nt) amv[nt] = namv[nt];
      __syncthreads();
      cur ^= 1;
    }
  }

  // ---- RMSNorm over d=64 and bf16 store ----
#pragma unroll
  for (int r = 0; r < 4; ++r) {
    float p = acc[0][r] * acc[0][r] + acc[1][r] * acc[1][r]
            + acc[2][r] * acc[2][r] + acc[3][r] * acc[3][r];
#pragma unroll
    for (int off = 1; off < 16; off <<= 1) p += __shfl_xor(p, off);
    const float rn = rsqrtf(p * (1.0f / 64.0f) + 1.1920928955078125e-07f);
    unsigned short* op =
        attn_out + (size_t)(l0 + w * 16 + quad * 4 + r) * HIDN + h * DHD + l16;
#pragma unroll
    for (int ds = 0; ds < 4; ++ds)
      op[ds * 16] = f2b(acc[ds][r] * rn * smallf[9216 + ds * 16 + l16]);
  }
}

extern "C" void kernel_launch(void* const* d_in, const int* in_sizes, int n_in,
                              void* d_out, int out_size, void* d_ws, size_t ws_size,
                              hipStream_t stream)
{
  (void)in_sizes; (void)n_in; (void)out_size; (void)ws_size;
  const void* hs        = d_in[0];
  // d_in[1] = attention_mask: deterministic causal triu — handled analytically
  const void* qkv_w     = d_in[2];
  const void* q_conv_w  = d_in[3];
  const void* q_conv_b  = d_in[4];
  const void* k_conv_w  = d_in[5];
  const void* k_conv_b  = d_in[6];
  const void* v_conv_w  = d_in[7];
  const void* v_conv_b  = d_in[8];
  const void* norm_w    = d_in[9];
  const void* A_log     = d_in[10];
  const void* dt_bias   = d_in[11];
  const void* dt_proj_w = d_in[12];
  const void* dt_proj_b = d_in[13];
  const void* o_w       = d_in[14];
  const void* ordc      = d_in[15];

  char* ws = (char*)d_ws;
  int* flag             = (int*)ws;                              // @0
  unsigned short* hs_b  = (unsigned short*)(ws + 256);           // 2097152*2
  unsigned short* qkvw_b= (unsigned short*)(ws + 4194560);       // 3145728*2
  unsigned short* ow_b  = (unsigned short*)(ws + 10486016);      // 1048576*2
  unsigned short* dtw_b = (unsigned short*)(ws + 12583168);      // 16384*2
  float* smallf         = (float*)(ws + 12615936);               // 9344*4
  float* qkv            = (float*)(ws + 12653568);               // 25165824 (fp32)
  unsigned short* qc_h  = (unsigned short*)(ws + 37819392);      // fp16 12.6MB
  float* dtbuf          = (float*)(ws + 62985216);               // 131072
  float* Abuf           = (float*)(ws + 63116288);               // 131072
  float* Acum           = (float*)(ws + 63247360);               // 131072
  unsigned short* attnb = (unsigned short*)(ws + 63378432);      // 2097152*2
  unsigned short* vt_h  = (unsigned short*)(ws + 67572736);      // 2097152*2 (V^T fp16)

  prep_kernel<<<1024, 256, 0, stream>>>(
      hs, qkv_w, o_w, dt_proj_w,
      q_conv_w, q_conv_b, k_conv_w, k_conv_b, v_conv_w, v_conv_b,
      norm_w, A_log, dt_bias, dt_proj_b, ordc,
      hs_b, qkvw_b, ow_b, dtw_b, smallf, flag);

  gemm128<<<dim3(QKV_N / 128, L_SEQ / 128), 256, 0, stream>>>(
      hs_b, qkvw_b, qkv, L_SEQ, QKV_N, HIDN);
  dt_kernel<<<L_SEQ, 256, 0, stream>>>(hs_b, dtw_b, smallf, dtbuf, Abuf);
  cumsum_kernel<<<NH, 64, 0, stream>>>(Abuf, Acum);
  conv_kernel<<<(L_SEQ * QKV_N / 4) / 256, 256, 0, stream>>>(qkv, smallf, dtbuf, qc_h);
  transpose_v<<<dim3(L_SEQ / 64, NH), 256, 0, stream>>>(qc_h, vt_h);
  attn_kernel<<<dim3(32, NH), 256, 0, stream>>>(qc_h, vt_h, Acum, smallf, attnb);
  gemm_bt<1><<<dim3(HIDN / 64, L_SEQ / 64), 256, 0, stream>>>(
      attnb, ow_b, d_out, L_SEQ, HIDN, HIDN, flag);
}